// Round 8
// baseline (203.569 us; speedup 1.0000x reference)
//
#include <hip/hip_runtime.h>
#include <math.h>

// GeoAttention on gfx950: B=2, S=2048, DIM=512, H=8, HD=64.
// bf16 MFMA (16x16x32) everywhere, fp32 accumulate.
// R16: qkv_mfma + out_mfma pipeline deepened: triple-buffer/distance-2
// (loads got ~1.5 steps vs 600-900cy L2-miss latency, m126) -> QUAD-buffer,
// prefetch distance 3, vmcnt(16) (two full stages in flight across each
// step; every load gets ~2.5 steps to land). LDS 24->32 KB, 5 blocks/CU.
// Same single-wave barrier-free structure (R14) — in-order LDS per wave
// makes the overwrite race-free (overwritten buffer was consumed last step).
// attn_mfma (R15: P-in-registers via pi-permuted vtT, j-split x2, exp2),
// combine_attn, preps unchanged.

typedef __attribute__((ext_vector_type(8))) short short8;
typedef __attribute__((ext_vector_type(4))) short bf16x4;
typedef __attribute__((ext_vector_type(4))) float f32x4;
typedef __attribute__((ext_vector_type(2))) float f32x2;
typedef __attribute__((ext_vector_type(4))) unsigned int u32x4;

#define MFMA(a, b, c) __builtin_amdgcn_mfma_f32_16x16x32_bf16((a), (b), (c), 0, 0, 0)

static __device__ __forceinline__ short f2bf(float f) {
    unsigned u = __float_as_uint(f);
    u += 0x7fffu + ((u >> 16) & 1u);          // round-to-nearest-even
    return (short)(u >> 16);
}

// global -> LDS direct DMA, 16B per lane, wave-uniform LDS base + lane*16
static __device__ __forceinline__ void gld_lds16(const short* g, short* l) {
    __builtin_amdgcn_global_load_lds(
        (const __attribute__((address_space(1))) unsigned int*)g,
        (__attribute__((address_space(3))) unsigned int*)l, 16, 0, 0);
}

// ---------------------------------------------------------------------------
// Prep 1: xb[4096][1024] bf16 = concat(x_real, x_imag)
// ---------------------------------------------------------------------------
__global__ __launch_bounds__(256) void convert_x(
    const float* __restrict__ xr, const float* __restrict__ xi,
    short* __restrict__ xb)
{
    int idx = blockIdx.x * 256 + threadIdx.x;
    int e = idx << 2;
    int m = e >> 10, k = e & 1023;
    const float* src = (k < 512) ? xr : xi;
    float4 t = *(const float4*)(src + (size_t)m * 512 + (k & 511));
    unsigned lo = (unsigned short)f2bf(t.x) | ((unsigned)(unsigned short)f2bf(t.y) << 16);
    unsigned hi = (unsigned short)f2bf(t.z) | ((unsigned)(unsigned short)f2bf(t.w) << 16);
    uint2 o; o.x = lo; o.y = hi;
    *(uint2*)(xb + e) = o;
}

// ---------------------------------------------------------------------------
// Prep 2: transpose + convert weights to bf16, n-major [N][K].
// wqt/wkt/wvt are contiguous in the workspace => single wcat[1536][1024].
// ---------------------------------------------------------------------------
__global__ __launch_bounds__(256) void transpose_w(
    const float* __restrict__ Wq, const float* __restrict__ Wk,
    const float* __restrict__ Wv, const float* __restrict__ Wo,
    short* __restrict__ wqt, short* __restrict__ wkt,
    short* __restrict__ wvt, short* __restrict__ wot)
{
    __shared__ float t[32][33];
    const int z = blockIdx.z;
    const float* src = (z == 0) ? Wq : (z == 1) ? Wk : (z == 2) ? Wv : Wo;
    short* dst = (z == 0) ? wqt : (z == 1) ? wkt : (z == 2) ? wvt : wot;
    const int K = (z < 3) ? 1024 : 512;
    const int N = (z < 3) ? 512 : 1024;
    const int n0 = blockIdx.x << 5, k0 = blockIdx.y << 5;
    if (n0 >= N || k0 >= K) return;
    const int tx = threadIdx.x & 31, ty = threadIdx.x >> 5;
    #pragma unroll
    for (int i = 0; i < 4; ++i)
        t[ty + 8 * i][tx] = src[(size_t)(k0 + ty + 8 * i) * N + n0 + tx];
    __syncthreads();
    #pragma unroll
    for (int i = 0; i < 4; ++i)
        dst[(size_t)(n0 + ty + 8 * i) * K + k0 + tx] = f2bf(t[tx][ty + 8 * i]);
}

// ---------------------------------------------------------------------------
// Kernel 1: QKV projection. Grid (24, 64), 64 threads = ONE wave, no barrier.
// Wave-private 64x64 tile, K=1024 (32 steps). R16: quad-buffer, prefetch
// distance 3, vmcnt(16) self-sync. jb: op = jb>>3, h = jb&7.
// ---------------------------------------------------------------------------
__global__ __launch_bounds__(64) void qkv_mfma(
    const short* __restrict__ xb, const short* __restrict__ wcat,
    const float* __restrict__ bq, const float* __restrict__ bk,
    const float* __restrict__ bv,
    short* __restrict__ sp, short* __restrict__ sq, short* __restrict__ vt)
{
    __shared__ short As[4][64 * 32];      // [row][k] 4KB per buffer
    __shared__ short Bs[4][64 * 32];      // [col][k] 4KB per buffer
    const int jb = blockIdx.x;            // 0..23
    const int m0 = blockIdx.y << 6;       // 64-row tile
    const int lane = threadIdx.x;
    const int l = lane & 15, quad = lane >> 4;

    const int srow = lane >> 2;
    const int sseg = (lane & 3) << 3;
    const short* gA = xb   + (size_t)(m0        + srow) * 1024 + sseg;
    const short* gB = wcat + (size_t)((jb << 6) + srow) * 1024 + sseg;

    auto STAGE = [&](int bb, int kk) {
        const int k0 = kk << 5;
        #pragma unroll
        for (int t = 0; t < 4; ++t) {
            gld_lds16(gA + k0 + t * 16 * 1024, &As[bb][t << 9]);
            gld_lds16(gB + k0 + t * 16 * 1024, &Bs[bb][t << 9]);
        }
    };

    // prologue: stage k-tiles 0,1,2; drain only tile 0 (16 = 2 stages stay)
    STAGE(0, 0);
    STAGE(1, 1);
    STAGE(2, 2);
    asm volatile("s_waitcnt vmcnt(16)" ::: "memory");

    const f32x4 z4 = {0.f, 0.f, 0.f, 0.f};
    f32x4 acc[4][4];
    #pragma unroll
    for (int i = 0; i < 4; ++i)
        #pragma unroll
        for (int j = 0; j < 4; ++j) acc[i][j] = z4;

    #pragma unroll 1
    for (int kt = 0; kt < 32; ++kt) {
        const int cb = kt & 3, sb = (kt + 3) & 3;
        STAGE(sb, (kt + 3) & 31);         // wrap re-stage at kt>=29: harmless
        const short* Al = &As[cb][0];
        const short* Bl = &Bs[cb][0];
        short8 af[4], bfr[4];
        #pragma unroll
        for (int i = 0; i < 4; ++i)
            af[i] = *(const short8*)(Al + (((i << 4) + l) << 5) + (quad << 3));
        #pragma unroll
        for (int j = 0; j < 4; ++j)
            bfr[j] = *(const short8*)(Bl + (((j << 4) + l) << 5) + (quad << 3));
        #pragma unroll
        for (int i = 0; i < 4; ++i)
            #pragma unroll
            for (int j = 0; j < 4; ++j)
                acc[i][j] = MFMA(af[i], bfr[j], acc[i][j]);
        // drain the stage needed NEXT step; the 2 newest stay in flight.
        asm volatile("s_waitcnt vmcnt(16)" ::: "memory");
    }

    const int op = jb >> 3;               // 0=Q 1=K 2=V
    const int h  = jb & 7;                // head for this block

    if (op < 2) {
        short* dst = (op == 0) ? sp : sq;
        const float* bias = (op == 0) ? bq : bk;
        float bcol[4];
        #pragma unroll
        for (int nt = 0; nt < 4; ++nt) bcol[nt] = bias[(h << 6) + (nt << 4) + l];
        #pragma unroll
        for (int i = 0; i < 4; ++i) {
            #pragma unroll
            for (int reg = 0; reg < 4; ++reg) {
                const int r = m0 + (i << 4) + (quad << 2) + reg;
                const int b = r >> 11, s = r & 2047;
                float v[4];
                #pragma unroll
                for (int nt = 0; nt < 4; ++nt) v[nt] = acc[i][nt][reg] + bcol[nt];
                float mx = fmaxf(fmaxf(v[0], v[1]), fmaxf(v[2], v[3]));
                #pragma unroll
                for (int msk = 1; msk < 16; msk <<= 1) mx = fmaxf(mx, __shfl_xor(mx, msk));
                float e[4], ssum = 0.f;
                #pragma unroll
                for (int nt = 0; nt < 4; ++nt) { e[nt] = __expf(v[nt] - mx); ssum += e[nt]; }
                #pragma unroll
                for (int msk = 1; msk < 16; msk <<= 1) ssum += __shfl_xor(ssum, msk);
                float inv = 1.0f / ssum;
                short* o = dst + ((size_t)((b << 3) + h) * 2048 + s) * 64 + l;
                #pragma unroll
                for (int nt = 0; nt < 4; ++nt)
                    o[nt << 4] = f2bf(sqrtf(e[nt] * inv));
            }
        }
    } else {
        float bcol[4];
        #pragma unroll
        for (int nt = 0; nt < 4; ++nt) bcol[nt] = bv[(h << 6) + (nt << 4) + l];
        #pragma unroll
        for (int i = 0; i < 4; ++i) {
            const int sb2 = m0 + (i << 4) + (quad << 2);
            const int b = sb2 >> 11, s = sb2 & 2047;
            #pragma unroll
            for (int nt = 0; nt < 4; ++nt) {
                const int d = (nt << 4) + l;
                bf16x4 pk;
                #pragma unroll
                for (int reg = 0; reg < 4; ++reg)
                    pk[reg] = f2bf(acc[i][nt][reg] + bcol[nt]);
                *(bf16x4*)(vt + ((size_t)((b << 3) + h) * 64 + d) * 2048 + s) = pk;
            }
        }
    }
}

// ---------------------------------------------------------------------------
// Kernel 2: attention partials. Grid (32, 16, 2), 256 threads = 4 waves.
// (unchanged R15) P-in-registers via pi-permuted vtT staging; j-split x2;
// poly pre-scaled by -log2(e), e = exp2(w).
// ---------------------------------------------------------------------------
__global__ __launch_bounds__(256, 4) void attn_mfma(
    const short* __restrict__ sp, const short* __restrict__ sq,
    const short* __restrict__ vt,
    float* __restrict__ pnum, float* __restrict__ pden)
{
    __shared__ __align__(16) short sqT[2][64 * 64];   // [j][d] swizzled
    __shared__ __align__(16) short vtT[2][64 * 64];   // [d][pi(j)] swizzled
    const int bh = blockIdx.y;
    const int m0 = blockIdx.x << 6;
    const int z  = blockIdx.z;            // j-half: jt in [16z, 16z+16)
    const int tid = threadIdx.x;
    const int w = tid >> 6, lane = tid & 63;
    const int l = lane & 15, quad = lane >> 4;
    const int l7 = l & 7;

    const short* spB = sp + (size_t)bh * 2048 * 64;
    const short* sqB = sq + (size_t)bh * 2048 * 64;
    const short* vtB = vt + (size_t)bh * 64 * 2048;

    // persistent sp frags (B-operand), negated: MFMA(sq,-sp,1) = 1-bc = u
    const short* apr = spB + (size_t)(m0 + w * 16 + l) * 64 + quad * 8;
    short8 nq0 = (*(const short8*)(apr)) ^ (short)0x8000;
    short8 nq1 = (*(const short8*)(apr + 32)) ^ (short)0x8000;

    // staging: thread -> tile row (tid>>2), 32B col chunk (tid&3)
    const int srow = tid >> 2;
    const int t3 = tid & 3;
    const int scol = t3 * 16;
    const short* sqG = sqB + (size_t)srow * 64 + scol;   // + j0*64 per jt
    const short* vtG = vtB + (size_t)srow * 2048 + scol; // + j0 per jt
    // sq staging: 2x b128 at XOR-swizzled 16B slots
    const int sl0 = t3 << 1;
    const int sw0 = srow * 64 + (((sl0    ) ^ (srow & 7)) << 3);
    const int sw1 = srow * 64 + (((sl0 | 1) ^ (srow & 7)) << 3);
    // vt staging: 4x ds_write_b64 at pi-permuted, XOR-swizzled slots
    int vwo[4];
    #pragma unroll
    for (int m = 0; m < 4; ++m)
        vwo[m] = srow * 64 + ((((t3 >> 1) * 4 + m) ^ (srow & 7)) << 3)
               + ((t3 & 1) << 2);

    // reader slot offset: rows read are (16*k + l) so row&7 == l7 everywhere
    const int sRd = (quad ^ l7) << 3;     // 16B-slot quad; ^32 -> slot quad+4

    // prologue: stage jt = 16z into buffer 0
    {
        const int j0 = (z << 4) << 6;
        short8 a0 = *(const short8*)(sqG + (size_t)j0 * 64);
        short8 a1 = *(const short8*)(sqG + (size_t)j0 * 64 + 8);
        short8 b0 = *(const short8*)(vtG + j0);
        short8 b1 = *(const short8*)(vtG + j0 + 8);
        *(short8*)(&sqT[0][sw0]) = a0;
        *(short8*)(&sqT[0][sw1]) = a1;
        u32x4 u0 = __builtin_bit_cast(u32x4, b0);
        u32x4 u1 = __builtin_bit_cast(u32x4, b1);
        *(uint2*)(&vtT[0][vwo[0]]) = (uint2){u0.x, u0.y};
        *(uint2*)(&vtT[0][vwo[1]]) = (uint2){u0.z, u0.w};
        *(uint2*)(&vtT[0][vwo[2]]) = (uint2){u1.x, u1.y};
        *(uint2*)(&vtT[0][vwo[3]]) = (uint2){u1.z, u1.w};
    }
    __syncthreads();

    const f32x4 ones4 = {1.f, 1.f, 1.f, 1.f};
    const f32x4 z4 = {0.f, 0.f, 0.f, 0.f};
    f32x4 acc[4] = {z4, z4, z4, z4};
    f32x2 den2 = {0.f, 0.f};

    #pragma unroll 1
    for (int jtl = 0; jtl < 16; ++jtl) {
        const int cb = jtl & 1, nb = cb ^ 1;
        const int j0n = ((z << 4) + ((jtl + 1) & 15)) << 6;  // wrap: harmless
        short8 na0 = *(const short8*)(sqG + (size_t)j0n * 64);
        short8 na1 = *(const short8*)(sqG + (size_t)j0n * 64 + 8);
        short8 nb0 = *(const short8*)(vtG + j0n);
        short8 nb1 = *(const short8*)(vtG + j0n + 8);

        // QK^T transposed: lane l = Q-row, 16nt+4q+reg = j-local; u = 1-bc
        uint2 pk[4];
        const short* sqL = &sqT[cb][0];
        #pragma unroll
        for (int nt = 0; nt < 4; ++nt) {
            const short* ar = sqL + ((nt * 16 + l) << 6);
            short8 sa0 = *(const short8*)(ar + sRd);
            short8 sa1 = *(const short8*)(ar + (sRd ^ 32));
            f32x4 p = MFMA(sa0, nq0, ones4);
            p = MFMA(sa1, nq1, p);
            // w = u * poly(u), coefficients pre-scaled by -log2(e)
            f32x2 u01 = {p[0], p[1]};
            f32x2 u23 = {p[2], p[3]};
            const f32x2 zz = {0.f, 0.f};
#if __has_builtin(__builtin_elementwise_max)
            u01 = __builtin_elementwise_max(u01, zz);
            u23 = __builtin_elementwise_max(u23, zz);
#else
            u01.x = fmaxf(u01.x, 0.f); u01.y = fmaxf(u01.y, 0.f);
            u23.x = fmaxf(u23.x, 0.f); u23.y = fmaxf(u23.y, 0.f);
#endif
            f32x2 t01 = {-0.00133017f, -0.00133017f};
            f32x2 t23 = t01;
            t01 = t01 * u01 - 0.00219618f;  t23 = t23 * u23 - 0.00219618f;
            t01 = t01 * u01 - 0.00555151f;  t23 = t23 * u23 - 0.00555151f;
            t01 = t01 * u01 - 0.01465597f;  t23 = t23 * u23 - 0.01465597f;
            t01 = t01 * u01 - 0.04121986f;  t23 = t23 * u23 - 0.04121986f;
            t01 = t01 * u01 - 0.12823956f;  t23 = t23 * u23 - 0.12823956f;
            t01 = t01 * u01 - 0.48089834f;  t23 = t23 * u23 - 0.48089834f;
            t01 = t01 * u01 - 2.88539008f;  t23 = t23 * u23 - 2.88539008f;
            f32x2 w01 = u01 * t01;          // <= 0
            f32x2 w23 = u23 * t23;
#if __has_builtin(__builtin_amdgcn_exp2f)
            float e0 = __builtin_amdgcn_exp2f(w01.x);
            float e1 = __builtin_amdgcn_exp2f(w01.y);
            float e2 = __builtin_amdgcn_exp2f(w23.x);
            float e3 = __builtin_amdgcn_exp2f(w23.y);
#else
            float e0 = exp2f(w01.x), e1 = exp2f(w01.y);
            float e2 = exp2f(w23.x), e3 = exp2f(w23.y);
#endif
            f32x2 es = {e0 + e2, e1 + e3};
            den2 += es;
            pk[nt].x = (__float_as_uint(e0) >> 16) | (__float_as_uint(e1) & 0xffff0000u);
            pk[nt].y = (__float_as_uint(e2) >> 16) | (__float_as_uint(e3) & 0xffff0000u);
        }

        // PV: pk registers ARE the A-frags (j-order matched by vtT staging)
        u32x4 c0; c0.x = pk[0].x; c0.y = pk[0].y; c0.z = pk[1].x; c0.w = pk[1].y;
        u32x4 c1; c1.x = pk[2].x; c1.y = pk[2].y; c1.z = pk[3].x; c1.w = pk[3].y;
        short8 pa0 = __builtin_bit_cast(short8, c0);
        short8 pa1 = __builtin_bit_cast(short8, c1);
        const short* vL = &vtT[cb][0];
        #pragma unroll
        for (int t4 = 0; t4 < 4; ++t4) {
            const short* vr = vL + ((t4 * 16 + l) << 6);
            short8 vb0 = *(const short8*)(vr + sRd);
            short8 vb1 = *(const short8*)(vr + (sRd ^ 32));
            acc[t4] = MFMA(pa0, vb0, acc[t4]);
            acc[t4] = MFMA(pa1, vb1, acc[t4]);
        }

        // write next tiles into the other buffer, then single barrier
        *(short8*)(&sqT[nb][sw0]) = na0;
        *(short8*)(&sqT[nb][sw1]) = na1;
        u32x4 u0 = __builtin_bit_cast(u32x4, nb0);
        u32x4 u1 = __builtin_bit_cast(u32x4, nb1);
        *(uint2*)(&vtT[nb][vwo[0]]) = (uint2){u0.x, u0.y};
        *(uint2*)(&vtT[nb][vwo[1]]) = (uint2){u0.z, u0.w};
        *(uint2*)(&vtT[nb][vwo[2]]) = (uint2){u1.x, u1.y};
        *(uint2*)(&vtT[nb][vwo[3]]) = (uint2){u1.z, u1.w};
        __syncthreads();
    }

    // den: sum across quads (each quad covered different j); lane<16 stores
    float den = den2.x + den2.y;
    den += __shfl_xor(den, 16);
    den += __shfl_xor(den, 32);
    if (lane < 16)
        pden[(size_t)z * 32768 + bh * 2048 + m0 + w * 16 + l] = den;

    // partial numerator, f32, no division
    const int b = bh >> 3, hh = bh & 7;
    float* np = pnum + (size_t)z * 4096 * 512;
    #pragma unroll
    for (int t4 = 0; t4 < 4; ++t4)
        #pragma unroll
        for (int reg = 0; reg < 4; ++reg) {
            const int row = m0 + w * 16 + quad * 4 + reg;
            np[((size_t)(b * 2048 + row)) * 512 + hh * 64 + t4 * 16 + l] =
                acc[t4][reg];
        }
}

// ---------------------------------------------------------------------------
// Kernel 2b: combine halves -> attB bf16. 2M elems, 8 per thread. (unchanged)
// ---------------------------------------------------------------------------
__global__ __launch_bounds__(256) void combine_attn(
    const float* __restrict__ pnum, const float* __restrict__ pden,
    short* __restrict__ attB)
{
    const int idx = (blockIdx.x * 256 + threadIdx.x) << 3;
    const int r = idx >> 9;               // 0..4095
    const int c = idx & 511;
    const int hh = c >> 6;
    const int bh = ((r >> 11) << 3) + hh;
    const int srow = r & 2047;
    const float d = pden[bh * 2048 + srow] + pden[32768 + bh * 2048 + srow];
    const float inv = 1.0f / d;
    const float* n0 = pnum + (size_t)r * 512 + c;
    const float* n1 = n0 + (size_t)4096 * 512;
    float4 a0 = *(const float4*)(n0);
    float4 a1 = *(const float4*)(n0 + 4);
    float4 b0 = *(const float4*)(n1);
    float4 b1 = *(const float4*)(n1 + 4);
    short8 o;
    o[0] = f2bf((a0.x + b0.x) * inv);
    o[1] = f2bf((a0.y + b0.y) * inv);
    o[2] = f2bf((a0.z + b0.z) * inv);
    o[3] = f2bf((a0.w + b0.w) * inv);
    o[4] = f2bf((a1.x + b1.x) * inv);
    o[5] = f2bf((a1.y + b1.y) * inv);
    o[6] = f2bf((a1.z + b1.z) * inv);
    o[7] = f2bf((a1.w + b1.w) * inv);
    *(short8*)(attB + idx) = o;
}

// ---------------------------------------------------------------------------
// Kernel 3: out = attB[4096][512](bf16) @ Wo + bo -> fp32.
// R16: quad-buffer, distance 3, vmcnt(16). Grid (16, 64), single wave.
// ---------------------------------------------------------------------------
__global__ __launch_bounds__(64) void out_mfma(
    const short* __restrict__ attB, const short* __restrict__ wot,
    const float* __restrict__ bo, float* __restrict__ out)
{
    __shared__ short As[4][64 * 32];      // 4KB per buffer
    __shared__ short Bs[4][64 * 32];      // 4KB per buffer
    const int n0 = blockIdx.x << 6;       // 64-col tile
    const int m0 = blockIdx.y << 6;       // 64-row tile
    const int lane = threadIdx.x;
    const int l = lane & 15, quad = lane >> 4;

    const int srow = lane >> 2;
    const int sseg = (lane & 3) << 3;
    const short* gA = attB + (size_t)(m0 + srow) * 512 + sseg;
    const short* gB = wot  + (size_t)(n0 + srow) * 512 + sseg;

    auto STAGE = [&](int bb, int kk) {
        const int k0 = kk << 5;
        #pragma unroll
        for (int t = 0; t < 4; ++t) {
            gld_lds16(gA + k0 + t * 16 * 512, &As[bb][t << 9]);
            gld_lds16(gB + k0 + t * 16 * 512, &Bs[bb][t << 9]);
        }
    };

    STAGE(0, 0);
    STAGE(1, 1);
    STAGE(2, 2);
    asm volatile("s_waitcnt vmcnt(16)" ::: "memory");

    const f32x4 z4 = {0.f, 0.f, 0.f, 0.f};
    f32x4 acc[4][4];
    #pragma unroll
    for (int i = 0; i < 4; ++i)
        #pragma unroll
        for (int j = 0; j < 4; ++j) acc[i][j] = z4;

    #pragma unroll 1
    for (int kt = 0; kt < 16; ++kt) {
        const int cb = kt & 3, sb = (kt + 3) & 3;
        STAGE(sb, (kt + 3) & 15);         // wrap re-stage at kt>=13: harmless
        const short* Al = &As[cb][0];
        const short* Bl = &Bs[cb][0];
        short8 af[4], bfr[4];
        #pragma unroll
        for (int i = 0; i < 4; ++i)
            af[i] = *(const short8*)(Al + (((i << 4) + l) << 5) + (quad << 3));
        #pragma unroll
        for (int j = 0; j < 4; ++j)
            bfr[j] = *(const short8*)(Bl + (((j << 4) + l) << 5) + (quad << 3));
        #pragma unroll
        for (int i = 0; i < 4; ++i)
            #pragma unroll
            for (int j = 0; j < 4; ++j)
                acc[i][j] = MFMA(af[i], bfr[j], acc[i][j]);
        asm volatile("s_waitcnt vmcnt(16)" ::: "memory");
    }

    float bcol[4];
    #pragma unroll
    for (int nt = 0; nt < 4; ++nt) bcol[nt] = bo[n0 + (nt << 4) + l];
    #pragma unroll
    for (int i = 0; i < 4; ++i)
        #pragma unroll
        for (int reg = 0; reg < 4; ++reg) {
            const int m = m0 + (i << 4) + (quad << 2) + reg;
            float* o = out + (size_t)m * 1024 + n0 + l;
            #pragma unroll
            for (int nt = 0; nt < 4; ++nt)
                o[nt << 4] = acc[i][nt][reg] + bcol[nt];
        }
}

// ---------------------------------------------------------------------------
extern "C" void kernel_launch(void* const* d_in, const int* in_sizes, int n_in,
                              void* d_out, int out_size, void* d_ws, size_t ws_size,
                              hipStream_t stream) {
    const float* xr = (const float*)d_in[0];
    const float* xi = (const float*)d_in[1];
    const float* Wq = (const float*)d_in[2];
    const float* bq = (const float*)d_in[3];
    const float* Wk = (const float*)d_in[4];
    const float* bk = (const float*)d_in[5];
    const float* Wv = (const float*)d_in[6];
    const float* bv = (const float*)d_in[7];
    const float* Wo = (const float*)d_in[8];
    const float* bo = (const float*)d_in[9];
    float* out = (float*)d_out;

    short* base = (short*)d_ws;
    short* xb   = base;                      // 4096*1024
    short* wqt  = xb  + 4194304;             // 512*1024  } contiguous =>
    short* wkt  = wqt + 524288;              // 512*1024  } wcat[1536][1024]
    short* wvt  = wkt + 524288;              // 512*1024  }
    short* wot  = wvt + 524288;              // 1024*512
    short* spW  = wot + 524288;              // 16*2048*64
    short* sqW  = spW + 2097152;
    short* vtW  = sqW + 2097152;             // [b,h,d,s]
    short* attB = vtW + 2097152;             // 4096*512
    float* pnum = (float*)(attB + 2097152);  // 2 x 4096*512 f32 = 16MB
    float* pden = pnum + 8388608;            // 2 x 16*2048 f32
    // total = 29,360,128 B + 16MB + 256KB ~= 46.4 MB

    hipLaunchKernelGGL(convert_x, dim3(4096), dim3(256), 0, stream, xr, xi, xb);
    hipLaunchKernelGGL(transpose_w, dim3(32, 32, 4), dim3(256), 0, stream,
                       Wq, Wk, Wv, Wo, wqt, wkt, wvt, wot);
    hipLaunchKernelGGL(qkv_mfma, dim3(24, 64), dim3(64), 0, stream,
                       xb, wqt, bq, bk, bv, spW, sqW, vtW);
    hipLaunchKernelGGL(attn_mfma, dim3(32, 16, 2), dim3(256), 0, stream,
                       spW, sqW, vtW, pnum, pden);
    hipLaunchKernelGGL(combine_attn, dim3(1024), dim3(256), 0, stream,
                       pnum, pden, attB);
    hipLaunchKernelGGL(out_mfma, dim3(16, 64), dim3(64), 0, stream,
                       attB, wot, bo, out);
}

// Round 9
// 187.488 us; speedup vs baseline: 1.0858x; 1.0858x over previous
//
#include <hip/hip_runtime.h>
#include <math.h>

// GeoAttention on gfx950: B=2, S=2048, DIM=512, H=8, HD=64.
// bf16 MFMA (16x16x32) everywhere, fp32 accumulate.
// R17: (a) REVERT R16's quad-buffer/distance-3 (regressed 80us: LDS 32KB cut
// residency, oldest-stage stall unchanged) back to R15's triple-buffer
// distance-2 vmcnt(8) single-wave GEMMs. (b) attn staging via
// global_load_lds with PRE-SWIZZLED GLOBAL layouts (m173/rule-21): qkv now
// writes sq with the XOR-unit permutation col'=((d>>3)^(s&7))*8+(d&7) and
// vt with the pi+XOR permutation (free — same stores, different address);
// attn stages both tiles with 4 DMA calls/wave/jt into LINEAR LDS whose
// image is byte-identical to the old swizzled ds_write layout. Read side
// unchanged. Deletes the VGPR round-trip, 6 ds_writes/thread/jt, and the
// write-side bank conflicts. attn compute (P-in-registers, j-split x2,
// exp2 poly) unchanged from R15.

typedef __attribute__((ext_vector_type(8))) short short8;
typedef __attribute__((ext_vector_type(4))) short bf16x4;
typedef __attribute__((ext_vector_type(4))) float f32x4;
typedef __attribute__((ext_vector_type(2))) float f32x2;
typedef __attribute__((ext_vector_type(4))) unsigned int u32x4;

#define MFMA(a, b, c) __builtin_amdgcn_mfma_f32_16x16x32_bf16((a), (b), (c), 0, 0, 0)

static __device__ __forceinline__ short f2bf(float f) {
    unsigned u = __float_as_uint(f);
    u += 0x7fffu + ((u >> 16) & 1u);          // round-to-nearest-even
    return (short)(u >> 16);
}

// global -> LDS direct DMA, 16B per lane, wave-uniform LDS base + lane*16
static __device__ __forceinline__ void gld_lds16(const short* g, short* l) {
    __builtin_amdgcn_global_load_lds(
        (const __attribute__((address_space(1))) unsigned int*)g,
        (__attribute__((address_space(3))) unsigned int*)l, 16, 0, 0);
}

// ---------------------------------------------------------------------------
// Prep 1: xb[4096][1024] bf16 = concat(x_real, x_imag)
// ---------------------------------------------------------------------------
__global__ __launch_bounds__(256) void convert_x(
    const float* __restrict__ xr, const float* __restrict__ xi,
    short* __restrict__ xb)
{
    int idx = blockIdx.x * 256 + threadIdx.x;
    int e = idx << 2;
    int m = e >> 10, k = e & 1023;
    const float* src = (k < 512) ? xr : xi;
    float4 t = *(const float4*)(src + (size_t)m * 512 + (k & 511));
    unsigned lo = (unsigned short)f2bf(t.x) | ((unsigned)(unsigned short)f2bf(t.y) << 16);
    unsigned hi = (unsigned short)f2bf(t.z) | ((unsigned)(unsigned short)f2bf(t.w) << 16);
    uint2 o; o.x = lo; o.y = hi;
    *(uint2*)(xb + e) = o;
}

// ---------------------------------------------------------------------------
// Prep 2: transpose + convert weights to bf16, n-major [N][K].
// wqt/wkt/wvt are contiguous in the workspace => single wcat[1536][1024].
// ---------------------------------------------------------------------------
__global__ __launch_bounds__(256) void transpose_w(
    const float* __restrict__ Wq, const float* __restrict__ Wk,
    const float* __restrict__ Wv, const float* __restrict__ Wo,
    short* __restrict__ wqt, short* __restrict__ wkt,
    short* __restrict__ wvt, short* __restrict__ wot)
{
    __shared__ float t[32][33];
    const int z = blockIdx.z;
    const float* src = (z == 0) ? Wq : (z == 1) ? Wk : (z == 2) ? Wv : Wo;
    short* dst = (z == 0) ? wqt : (z == 1) ? wkt : (z == 2) ? wvt : wot;
    const int K = (z < 3) ? 1024 : 512;
    const int N = (z < 3) ? 512 : 1024;
    const int n0 = blockIdx.x << 5, k0 = blockIdx.y << 5;
    if (n0 >= N || k0 >= K) return;
    const int tx = threadIdx.x & 31, ty = threadIdx.x >> 5;
    #pragma unroll
    for (int i = 0; i < 4; ++i)
        t[ty + 8 * i][tx] = src[(size_t)(k0 + ty + 8 * i) * N + n0 + tx];
    __syncthreads();
    #pragma unroll
    for (int i = 0; i < 4; ++i)
        dst[(size_t)(n0 + ty + 8 * i) * K + k0 + tx] = f2bf(t[tx][ty + 8 * i]);
}

// ---------------------------------------------------------------------------
// Kernel 1: QKV projection. Grid (24, 64), 64 threads = ONE wave, no barrier.
// Wave-private 64x64 tile, K=1024 (32 steps), TRIPLE-buffer, distance 2,
// vmcnt(8) self-sync (R15 config — measured best).
// Epilogue R17: sq written PRE-SWIZZLED (col' = ((d>>3)^(s&7))*8 + (d&7));
// vt written with the pi+XOR permutation. sp stays linear (register reads).
// ---------------------------------------------------------------------------
__global__ __launch_bounds__(64) void qkv_mfma(
    const short* __restrict__ xb, const short* __restrict__ wcat,
    const float* __restrict__ bq, const float* __restrict__ bk,
    const float* __restrict__ bv,
    short* __restrict__ sp, short* __restrict__ sq, short* __restrict__ vt)
{
    __shared__ short As[3][64 * 32];      // [row][k] 4KB per buffer
    __shared__ short Bs[3][64 * 32];      // [col][k] 4KB per buffer
    const int jb = blockIdx.x;            // 0..23
    const int m0 = blockIdx.y << 6;       // 64-row tile
    const int lane = threadIdx.x;
    const int l = lane & 15, quad = lane >> 4;
    const int l7 = l & 7;

    const int srow = lane >> 2;
    const int sseg = (lane & 3) << 3;
    const short* gA = xb   + (size_t)(m0        + srow) * 1024 + sseg;
    const short* gB = wcat + (size_t)((jb << 6) + srow) * 1024 + sseg;

    auto STAGE = [&](int bb, int kk) {
        const int k0 = kk << 5;
        #pragma unroll
        for (int t = 0; t < 4; ++t) {
            gld_lds16(gA + k0 + t * 16 * 1024, &As[bb][t << 9]);
            gld_lds16(gB + k0 + t * 16 * 1024, &Bs[bb][t << 9]);
        }
    };

    STAGE(0, 0);
    STAGE(1, 1);
    asm volatile("s_waitcnt vmcnt(8)" ::: "memory");

    const f32x4 z4 = {0.f, 0.f, 0.f, 0.f};
    f32x4 acc[4][4];
    #pragma unroll
    for (int i = 0; i < 4; ++i)
        #pragma unroll
        for (int j = 0; j < 4; ++j) acc[i][j] = z4;

    int cb = 0, sb = 2;
    #pragma unroll 1
    for (int kt = 0; kt < 32; ++kt) {
        STAGE(sb, (kt + 2) & 31);         // wrap re-stage at kt=30,31: harmless
        const short* Al = &As[cb][0];
        const short* Bl = &Bs[cb][0];
        short8 af[4], bfr[4];
        #pragma unroll
        for (int i = 0; i < 4; ++i)
            af[i] = *(const short8*)(Al + (((i << 4) + l) << 5) + (quad << 3));
        #pragma unroll
        for (int j = 0; j < 4; ++j)
            bfr[j] = *(const short8*)(Bl + (((j << 4) + l) << 5) + (quad << 3));
        #pragma unroll
        for (int i = 0; i < 4; ++i)
            #pragma unroll
            for (int j = 0; j < 4; ++j)
                acc[i][j] = MFMA(af[i], bfr[j], acc[i][j]);
        asm volatile("s_waitcnt vmcnt(8)" ::: "memory");
        cb = (cb == 2) ? 0 : cb + 1;
        sb = (sb == 2) ? 0 : sb + 1;
    }

    const int op = jb >> 3;               // 0=Q 1=K 2=V
    const int h  = jb & 7;                // head for this block

    if (op < 2) {
        short* dst = (op == 0) ? sp : sq;
        const float* bias = (op == 0) ? bq : bk;
        float bcol[4];
        #pragma unroll
        for (int nt = 0; nt < 4; ++nt) bcol[nt] = bias[(h << 6) + (nt << 4) + l];
        #pragma unroll
        for (int i = 0; i < 4; ++i) {
            #pragma unroll
            for (int reg = 0; reg < 4; ++reg) {
                const int r = m0 + (i << 4) + (quad << 2) + reg;
                const int b = r >> 11, s = r & 2047;
                float v[4];
                #pragma unroll
                for (int nt = 0; nt < 4; ++nt) v[nt] = acc[i][nt][reg] + bcol[nt];
                float mx = fmaxf(fmaxf(v[0], v[1]), fmaxf(v[2], v[3]));
                #pragma unroll
                for (int msk = 1; msk < 16; msk <<= 1) mx = fmaxf(mx, __shfl_xor(mx, msk));
                float e[4], ssum = 0.f;
                #pragma unroll
                for (int nt = 0; nt < 4; ++nt) { e[nt] = __expf(v[nt] - mx); ssum += e[nt]; }
                #pragma unroll
                for (int msk = 1; msk < 16; msk <<= 1) ssum += __shfl_xor(ssum, msk);
                float inv = 1.0f / ssum;
                short* o = dst + ((size_t)((b << 3) + h) * 2048 + s) * 64;
                if (op == 0) {
                    #pragma unroll
                    for (int nt = 0; nt < 4; ++nt)
                        o[(nt << 4) + l] = f2bf(sqrtf(e[nt] * inv));
                } else {
                    const int s7 = r & 7;
                    #pragma unroll
                    for (int nt = 0; nt < 4; ++nt)
                        o[((((nt << 1) + (l >> 3)) ^ s7) << 3) + l7] =
                            f2bf(sqrtf(e[nt] * inv));
                }
            }
        }
    } else {
        // V: store transposed + pi/XOR-permuted so attn can DMA-stage it.
        // element (d, s): gg=(s>>2)&15, u=4*(gg>>3)+(gg&3),
        // colp = (s&~63) + ((u^(d&7))<<3) + (((gg>>2)&1)<<2); d&7 == l7.
        float bcol[4];
        #pragma unroll
        for (int nt = 0; nt < 4; ++nt) bcol[nt] = bv[(h << 6) + (nt << 4) + l];
        #pragma unroll
        for (int i = 0; i < 4; ++i) {
            const int sb2 = m0 + (i << 4) + (quad << 2);
            const int b = sb2 >> 11, s = sb2 & 2047;
            const int gg = (s >> 2) & 15;
            const int u = ((gg >> 3) << 2) + (gg & 3);
            const int colp = (s & ~63) + (((u ^ l7)) << 3) + (((gg >> 2) & 1) << 2);
            #pragma unroll
            for (int nt = 0; nt < 4; ++nt) {
                const int d = (nt << 4) + l;
                bf16x4 pk;
                #pragma unroll
                for (int reg = 0; reg < 4; ++reg)
                    pk[reg] = f2bf(acc[i][nt][reg] + bcol[nt]);
                *(bf16x4*)(vt + ((size_t)((b << 3) + h) * 64 + d) * 2048 + colp) = pk;
            }
        }
    }
}

// ---------------------------------------------------------------------------
// Kernel 2: attention partials. Grid (32, 16, 2), 256 threads = 4 waves.
// R17: both tiles DMA-staged via global_load_lds into LINEAR LDS whose image
// equals the old swizzled layout (sources pre-swizzled by qkv). Wave w
// stages 1KB calls {2w,2w+1} of each tile. Reads + compute unchanged (R15:
// P-in-registers via permuted vtT, j-split x2, exp2 poly).
// ---------------------------------------------------------------------------
__global__ __launch_bounds__(256, 4) void attn_mfma(
    const short* __restrict__ sp, const short* __restrict__ sq,
    const short* __restrict__ vt,
    float* __restrict__ pnum, float* __restrict__ pden)
{
    __shared__ __align__(16) short sqT[2][64 * 64];   // [j][d] swizzled image
    __shared__ __align__(16) short vtT[2][64 * 64];   // [d][pi(j)] swizzled image
    const int bh = blockIdx.y;
    const int m0 = blockIdx.x << 6;
    const int z  = blockIdx.z;            // j-half: jt in [16z, 16z+16)
    const int tid = threadIdx.x;
    const int w = tid >> 6, lane = tid & 63;
    const int l = lane & 15, quad = lane >> 4;
    const int l7 = l & 7;

    const short* spB = sp + (size_t)bh * 2048 * 64;
    const short* sqB = sq + (size_t)bh * 2048 * 64;
    const short* vtB = vt + (size_t)bh * 64 * 2048;

    // persistent sp frags (B-operand), negated: MFMA(sq,-sp,1) = 1-bc = u
    const short* apr = spB + (size_t)(m0 + w * 16 + l) * 64 + quad * 8;
    short8 nq0 = (*(const short8*)(apr)) ^ (short)0x8000;
    short8 nq1 = (*(const short8*)(apr + 32)) ^ (short)0x8000;

    // DMA staging: call r covers rows 8r..8r+7 (1KB); lane -> row 8r+(lane>>3),
    // 16B unit (lane&7). Wave w owns calls {2w, 2w+1} of each tile.
    const int lr = lane >> 3;
    const int lu = lane & 7;
    const int r0 = w << 1;

    auto STAGEATT = [&](int buf, int jrow) {
        #pragma unroll
        for (int k = 0; k < 2; ++k) {
            const int r = r0 + k;
            gld_lds16(sqB + (size_t)(jrow + (r << 3) + lr) * 64 + (lu << 3),
                      &sqT[buf][r << 9]);
            gld_lds16(vtB + (size_t)((r << 3) + lr) * 2048 + jrow + (lu << 3),
                      &vtT[buf][r << 9]);
        }
    };

    // reader slot offset: rows read are (16*k + l) so row&7 == l7 everywhere
    const int sRd = (quad ^ l7) << 3;     // 16B-slot quad; ^32 -> slot quad+4

    // prologue: stage jt = 16z into buffer 0
    STAGEATT(0, z << 10);
    __syncthreads();

    const f32x4 ones4 = {1.f, 1.f, 1.f, 1.f};
    const f32x4 z4 = {0.f, 0.f, 0.f, 0.f};
    f32x4 acc[4] = {z4, z4, z4, z4};
    f32x2 den2 = {0.f, 0.f};

    #pragma unroll 1
    for (int jtl = 0; jtl < 16; ++jtl) {
        const int cb = jtl & 1, nb = cb ^ 1;
        const int j0n = (z << 10) + (((jtl + 1) & 15) << 6);  // wrap: harmless
        STAGEATT(nb, j0n);   // DMA into the buffer not read this iteration

        // QK^T transposed: lane l = Q-row, 16nt+4q+reg = j-local; u = 1-bc
        uint2 pk[4];
        const short* sqL = &sqT[cb][0];
        #pragma unroll
        for (int nt = 0; nt < 4; ++nt) {
            const short* ar = sqL + ((nt * 16 + l) << 6);
            short8 sa0 = *(const short8*)(ar + sRd);
            short8 sa1 = *(const short8*)(ar + (sRd ^ 32));
            f32x4 p = MFMA(sa0, nq0, ones4);
            p = MFMA(sa1, nq1, p);
            // w = u * poly(u), coefficients pre-scaled by -log2(e)
            f32x2 u01 = {p[0], p[1]};
            f32x2 u23 = {p[2], p[3]};
            const f32x2 zz = {0.f, 0.f};
#if __has_builtin(__builtin_elementwise_max)
            u01 = __builtin_elementwise_max(u01, zz);
            u23 = __builtin_elementwise_max(u23, zz);
#else
            u01.x = fmaxf(u01.x, 0.f); u01.y = fmaxf(u01.y, 0.f);
            u23.x = fmaxf(u23.x, 0.f); u23.y = fmaxf(u23.y, 0.f);
#endif
            f32x2 t01 = {-0.00133017f, -0.00133017f};
            f32x2 t23 = t01;
            t01 = t01 * u01 - 0.00219618f;  t23 = t23 * u23 - 0.00219618f;
            t01 = t01 * u01 - 0.00555151f;  t23 = t23 * u23 - 0.00555151f;
            t01 = t01 * u01 - 0.01465597f;  t23 = t23 * u23 - 0.01465597f;
            t01 = t01 * u01 - 0.04121986f;  t23 = t23 * u23 - 0.04121986f;
            t01 = t01 * u01 - 0.12823956f;  t23 = t23 * u23 - 0.12823956f;
            t01 = t01 * u01 - 0.48089834f;  t23 = t23 * u23 - 0.48089834f;
            t01 = t01 * u01 - 2.88539008f;  t23 = t23 * u23 - 2.88539008f;
            f32x2 w01 = u01 * t01;          // <= 0
            f32x2 w23 = u23 * t23;
#if __has_builtin(__builtin_amdgcn_exp2f)
            float e0 = __builtin_amdgcn_exp2f(w01.x);
            float e1 = __builtin_amdgcn_exp2f(w01.y);
            float e2 = __builtin_amdgcn_exp2f(w23.x);
            float e3 = __builtin_amdgcn_exp2f(w23.y);
#else
            float e0 = exp2f(w01.x), e1 = exp2f(w01.y);
            float e2 = exp2f(w23.x), e3 = exp2f(w23.y);
#endif
            f32x2 es = {e0 + e2, e1 + e3};
            den2 += es;
            pk[nt].x = (__float_as_uint(e0) >> 16) | (__float_as_uint(e1) & 0xffff0000u);
            pk[nt].y = (__float_as_uint(e2) >> 16) | (__float_as_uint(e3) & 0xffff0000u);
        }

        // PV: pk registers ARE the A-frags (j-order matched by vt layout)
        u32x4 c0; c0.x = pk[0].x; c0.y = pk[0].y; c0.z = pk[1].x; c0.w = pk[1].y;
        u32x4 c1; c1.x = pk[2].x; c1.y = pk[2].y; c1.z = pk[3].x; c1.w = pk[3].y;
        short8 pa0 = __builtin_bit_cast(short8, c0);
        short8 pa1 = __builtin_bit_cast(short8, c1);
        const short* vL = &vtT[cb][0];
        #pragma unroll
        for (int t4 = 0; t4 < 4; ++t4) {
            const short* vr = vL + ((t4 * 16 + l) << 6);
            short8 vb0 = *(const short8*)(vr + sRd);
            short8 vb1 = *(const short8*)(vr + (sRd ^ 32));
            acc[t4] = MFMA(pa0, vb0, acc[t4]);
            acc[t4] = MFMA(pa1, vb1, acc[t4]);
        }

        // barrier: compiler drains vmcnt(0) -> DMA for nb has landed
        __syncthreads();
    }

    // den: sum across quads (each quad covered different j); lane<16 stores
    float den = den2.x + den2.y;
    den += __shfl_xor(den, 16);
    den += __shfl_xor(den, 32);
    if (lane < 16)
        pden[(size_t)z * 32768 + bh * 2048 + m0 + w * 16 + l] = den;

    // partial numerator, f32, no division
    const int b = bh >> 3, hh = bh & 7;
    float* np = pnum + (size_t)z * 4096 * 512;
    #pragma unroll
    for (int t4 = 0; t4 < 4; ++t4)
        #pragma unroll
        for (int reg = 0; reg < 4; ++reg) {
            const int row = m0 + w * 16 + quad * 4 + reg;
            np[((size_t)(b * 2048 + row)) * 512 + hh * 64 + t4 * 16 + l] =
                acc[t4][reg];
        }
}

// ---------------------------------------------------------------------------
// Kernel 2b: combine halves -> attB bf16. 2M elems, 8 per thread. (unchanged)
// ---------------------------------------------------------------------------
__global__ __launch_bounds__(256) void combine_attn(
    const float* __restrict__ pnum, const float* __restrict__ pden,
    short* __restrict__ attB)
{
    const int idx = (blockIdx.x * 256 + threadIdx.x) << 3;
    const int r = idx >> 9;               // 0..4095
    const int c = idx & 511;
    const int hh = c >> 6;
    const int bh = ((r >> 11) << 3) + hh;
    const int srow = r & 2047;
    const float d = pden[bh * 2048 + srow] + pden[32768 + bh * 2048 + srow];
    const float inv = 1.0f / d;
    const float* n0 = pnum + (size_t)r * 512 + c;
    const float* n1 = n0 + (size_t)4096 * 512;
    float4 a0 = *(const float4*)(n0);
    float4 a1 = *(const float4*)(n0 + 4);
    float4 b0 = *(const float4*)(n1);
    float4 b1 = *(const float4*)(n1 + 4);
    short8 o;
    o[0] = f2bf((a0.x + b0.x) * inv);
    o[1] = f2bf((a0.y + b0.y) * inv);
    o[2] = f2bf((a0.z + b0.z) * inv);
    o[3] = f2bf((a0.w + b0.w) * inv);
    o[4] = f2bf((a1.x + b1.x) * inv);
    o[5] = f2bf((a1.y + b1.y) * inv);
    o[6] = f2bf((a1.z + b1.z) * inv);
    o[7] = f2bf((a1.w + b1.w) * inv);
    *(short8*)(attB + idx) = o;
}

// ---------------------------------------------------------------------------
// Kernel 3: out = attB[4096][512](bf16) @ Wo + bo -> fp32. (R15 config)
// Barrier-free single-wave blocks, grid (16, 64), triple-buffer, vmcnt(8).
// ---------------------------------------------------------------------------
__global__ __launch_bounds__(64) void out_mfma(
    const short* __restrict__ attB, const short* __restrict__ wot,
    const float* __restrict__ bo, float* __restrict__ out)
{
    __shared__ short As[3][64 * 32];      // 4KB per buffer
    __shared__ short Bs[3][64 * 32];      // 4KB per buffer
    const int n0 = blockIdx.x << 6;       // 64-col tile
    const int m0 = blockIdx.y << 6;       // 64-row tile
    const int lane = threadIdx.x;
    const int l = lane & 15, quad = lane >> 4;

    const int srow = lane >> 2;
    const int sseg = (lane & 3) << 3;
    const short* gA = attB + (size_t)(m0 + srow) * 512 + sseg;
    const short* gB = wot  + (size_t)(n0 + srow) * 512 + sseg;

    auto STAGE = [&](int bb, int kk) {
        const int k0 = kk << 5;
        #pragma unroll
        for (int t = 0; t < 4; ++t) {
            gld_lds16(gA + k0 + t * 16 * 512, &As[bb][t << 9]);
            gld_lds16(gB + k0 + t * 16 * 512, &Bs[bb][t << 9]);
        }
    };

    STAGE(0, 0);
    STAGE(1, 1);
    asm volatile("s_waitcnt vmcnt(8)" ::: "memory");

    const f32x4 z4 = {0.f, 0.f, 0.f, 0.f};
    f32x4 acc[4][4];
    #pragma unroll
    for (int i = 0; i < 4; ++i)
        #pragma unroll
        for (int j = 0; j < 4; ++j) acc[i][j] = z4;

    int cb = 0, sb = 2;
    #pragma unroll 1
    for (int kt = 0; kt < 16; ++kt) {
        STAGE(sb, (kt + 2) & 15);         // wrap re-stage at kt=14,15: harmless
        const short* Al = &As[cb][0];
        const short* Bl = &Bs[cb][0];
        short8 af[4], bfr[4];
        #pragma unroll
        for (int i = 0; i < 4; ++i)
            af[i] = *(const short8*)(Al + (((i << 4) + l) << 5) + (quad << 3));
        #pragma unroll
        for (int j = 0; j < 4; ++j)
            bfr[j] = *(const short8*)(Bl + (((j << 4) + l) << 5) + (quad << 3));
        #pragma unroll
        for (int i = 0; i < 4; ++i)
            #pragma unroll
            for (int j = 0; j < 4; ++j)
                acc[i][j] = MFMA(af[i], bfr[j], acc[i][j]);
        asm volatile("s_waitcnt vmcnt(8)" ::: "memory");
        cb = (cb == 2) ? 0 : cb + 1;
        sb = (sb == 2) ? 0 : sb + 1;
    }

    float bcol[4];
    #pragma unroll
    for (int nt = 0; nt < 4; ++nt) bcol[nt] = bo[n0 + (nt << 4) + l];
    #pragma unroll
    for (int i = 0; i < 4; ++i)
        #pragma unroll
        for (int reg = 0; reg < 4; ++reg) {
            const int m = m0 + (i << 4) + (quad << 2) + reg;
            float* o = out + (size_t)m * 1024 + n0 + l;
            #pragma unroll
            for (int nt = 0; nt < 4; ++nt)
                o[nt << 4] = acc[i][nt][reg] + bcol[nt];
        }
}

// ---------------------------------------------------------------------------
extern "C" void kernel_launch(void* const* d_in, const int* in_sizes, int n_in,
                              void* d_out, int out_size, void* d_ws, size_t ws_size,
                              hipStream_t stream) {
    const float* xr = (const float*)d_in[0];
    const float* xi = (const float*)d_in[1];
    const float* Wq = (const float*)d_in[2];
    const float* bq = (const float*)d_in[3];
    const float* Wk = (const float*)d_in[4];
    const float* bk = (const float*)d_in[5];
    const float* Wv = (const float*)d_in[6];
    const float* bv = (const float*)d_in[7];
    const float* Wo = (const float*)d_in[8];
    const float* bo = (const float*)d_in[9];
    float* out = (float*)d_out;

    short* base = (short*)d_ws;
    short* xb   = base;                      // 4096*1024
    short* wqt  = xb  + 4194304;             // 512*1024  } contiguous =>
    short* wkt  = wqt + 524288;              // 512*1024  } wcat[1536][1024]
    short* wvt  = wkt + 524288;              // 512*1024  }
    short* wot  = wvt + 524288;              // 1024*512
    short* spW  = wot + 524288;              // 16*2048*64
    short* sqW  = spW + 2097152;             // pre-swizzled layout
    short* vtW  = sqW + 2097152;             // [b,h,d,s] pi+XOR-permuted
    short* attB = vtW + 2097152;             // 4096*512
    float* pnum = (float*)(attB + 2097152);  // 2 x 4096*512 f32 = 16MB
    float* pden = pnum + 8388608;            // 2 x 16*2048 f32
    // total = 29,360,128 B + 16MB + 256KB ~= 46.4 MB

    hipLaunchKernelGGL(convert_x, dim3(4096), dim3(256), 0, stream, xr, xi, xb);
    hipLaunchKernelGGL(transpose_w, dim3(32, 32, 4), dim3(256), 0, stream,
                       Wq, Wk, Wv, Wo, wqt, wkt, wvt, wot);
    hipLaunchKernelGGL(qkv_mfma, dim3(24, 64), dim3(64), 0, stream,
                       xb, wqt, bq, bk, bv, spW, sqW, vtW);
    hipLaunchKernelGGL(attn_mfma, dim3(32, 16, 2), dim3(256), 0, stream,
                       spW, sqW, vtW, pnum, pden);
    hipLaunchKernelGGL(combine_attn, dim3(1024), dim3(256), 0, stream,
                       pnum, pden, attB);
    hipLaunchKernelGGL(out_mfma, dim3(16, 64), dim3(64), 0, stream,
                       attB, wot, bo, out);
}

// Round 10
// 184.310 us; speedup vs baseline: 1.1045x; 1.0172x over previous
//
#include <hip/hip_runtime.h>
#include <math.h>

// GeoAttention on gfx950: B=2, S=2048, DIM=512, H=8, HD=64.
// bf16 MFMA (16x16x32) everywhere, fp32 accumulate.
// R18: (1) qkv/out LDS tiles re-packed 64x64B -> 32x128B rows with XOR-slot
// layout; permutation folded into the GLOBAL layouts of xb/wcat (prep) and
// attB (combine) / wot (prep) so global_load_lds stays linear (m173).
// Kills qkv's 1.57M 8-way phase conflicts (attn's identical fix measured 0).
// Read slot: p = (((l&1)<<2)|quad) ^ ((l>>1)&7), addr = i*512+(l>>1)*64+p*8.
// (2) attn j-split x2 -> x4 (grid z=4, 8 jt each): 2048 blocks = 8/CU
// dispatched (was 4, grid-limited), 5 resident via 32KB LDS -> ~20 waves/CU.
// (3) convert_x + transpose_w merged into one prep_all launch.
// attn compute (P-in-registers, DMA-staged pre-swizzled K/V, exp2 poly)
// unchanged from R17.

typedef __attribute__((ext_vector_type(8))) short short8;
typedef __attribute__((ext_vector_type(4))) short bf16x4;
typedef __attribute__((ext_vector_type(4))) float f32x4;
typedef __attribute__((ext_vector_type(2))) float f32x2;
typedef __attribute__((ext_vector_type(4))) unsigned int u32x4;

#define MFMA(a, b, c) __builtin_amdgcn_mfma_f32_16x16x32_bf16((a), (b), (c), 0, 0, 0)

static __device__ __forceinline__ short f2bf(float f) {
    unsigned u = __float_as_uint(f);
    u += 0x7fffu + ((u >> 16) & 1u);          // round-to-nearest-even
    return (short)(u >> 16);
}

// global -> LDS direct DMA, 16B per lane, wave-uniform LDS base + lane*16
static __device__ __forceinline__ void gld_lds16(const short* g, short* l) {
    __builtin_amdgcn_global_load_lds(
        (const __attribute__((address_space(1))) unsigned int*)g,
        (__attribute__((address_space(3))) unsigned int*)l, 16, 0, 0);
}

// ---------------------------------------------------------------------------
// Prep: xb (swizzle-packed) + weight transposes (wcat/wot swizzle-packed).
// Swizzle-packed [NB][KT][32 r'][8 p][8] layout for a [64r][32k]-short tile:
//   r' = r>>1, u' = ((r&1)<<2)|(unit u = (k>>3)&3), p = u' ^ (r'&7).
// DMA call t stages LDS bytes [1024t,1024t+1024) linearly = r' in [8t,8t+8).
// ---------------------------------------------------------------------------
__global__ __launch_bounds__(256) void prep_all(
    const float* __restrict__ xr, const float* __restrict__ xi,
    short* __restrict__ xb,
    const float* __restrict__ Wq, const float* __restrict__ Wk,
    const float* __restrict__ Wv, const float* __restrict__ Wo,
    short* __restrict__ wqt, short* __restrict__ wot)
{
    const int bid = blockIdx.x;
    if (bid < 2048) {
        // convert_x: one 16B dst unit (8 bf16) per thread, write-coalesced.
        const unsigned wid = bid * 256 + threadIdx.x;   // dst = xb + wid*8
        const int p  = wid & 7;
        const int rp = (wid >> 3) & 31;
        const int kt = (wid >> 8) & 31;
        const int mb = wid >> 13;
        const int up = p ^ (rp & 7);
        const int m  = (mb << 6) | (rp << 1) | (up >> 2);
        const int k  = (kt << 5) | ((up & 3) << 3);
        const float* s = (k < 512) ? (xr + (size_t)m * 512 + k)
                                   : (xi + (size_t)m * 512 + (k - 512));
        float4 t0 = *(const float4*)(s);
        float4 t1 = *(const float4*)(s + 4);
        short8 o;
        o[0] = f2bf(t0.x); o[1] = f2bf(t0.y); o[2] = f2bf(t0.z); o[3] = f2bf(t0.w);
        o[4] = f2bf(t1.x); o[5] = f2bf(t1.y); o[6] = f2bf(t1.z); o[7] = f2bf(t1.w);
        *(short8*)(xb + (size_t)wid * 8) = o;
    } else {
        __shared__ float tt[32][33];
        const int t = bid - 2048;
        const int z = t >> 9;
        const int idx = t & 511;
        const float* src = (z == 0) ? Wq : (z == 1) ? Wk : (z == 2) ? Wv : Wo;
        const int N = (z < 3) ? 512 : 1024;
        const int bx = (z < 3) ? (idx & 15) : (idx & 31);
        const int by = (z < 3) ? (idx >> 4) : (idx >> 5);
        const int n0 = bx << 5, k0 = by << 5;
        const int tx = threadIdx.x & 31, ty = threadIdx.x >> 5;
        #pragma unroll
        for (int i = 0; i < 4; ++i)
            tt[ty + 8 * i][tx] = src[(size_t)(k0 + ty + 8 * i) * N + n0 + tx];
        __syncthreads();
        const int k = k0 + tx;
        const int kt = k >> 5, u = (k >> 3) & 3, off = k & 7;
        #pragma unroll
        for (int i = 0; i < 4; ++i) {
            const int n = n0 + ty + 8 * i;
            const int nb = n >> 6, rn = n & 63;
            const int rp = rn >> 1;
            const int up = ((rn & 1) << 2) | u;
            const int p  = up ^ (rp & 7);
            const float v = tt[tx][ty + 8 * i];
            if (z < 3)
                wqt[(size_t)z * 524288 +
                    ((size_t)(nb * 32 + kt)) * 2048 + rp * 64 + p * 8 + off] = f2bf(v);
            else
                wot[((size_t)(nb * 16 + kt)) * 2048 + rp * 64 + p * 8 + off] = f2bf(v);
        }
    }
}

// ---------------------------------------------------------------------------
// Kernel 1: QKV projection. Grid (24, 64), 64 threads = ONE wave, no barrier.
// Wave-private 64x64 tile, K=1024 (32 steps), triple-buffer, distance 2,
// vmcnt(8). R18: swizzle-packed xb/wcat -> linear DMA + conflict-free reads.
// Epilogue (R17): sq stored XOR-pre-swizzled, vt stored pi+XOR-permuted.
// ---------------------------------------------------------------------------
__global__ __launch_bounds__(64) void qkv_mfma(
    const short* __restrict__ xb, const short* __restrict__ wcat,
    const float* __restrict__ bq, const float* __restrict__ bk,
    const float* __restrict__ bv,
    short* __restrict__ sp, short* __restrict__ sq, short* __restrict__ vt)
{
    __shared__ short As[3][64 * 32];      // 4KB per buffer (32 r' x 128B)
    __shared__ short Bs[3][64 * 32];
    const int jb = blockIdx.x;            // 0..23
    const int mb = blockIdx.y;            // 0..63
    const int m0 = mb << 6;
    const int lane = threadIdx.x;
    const int l = lane & 15, quad = lane >> 4;
    const int l7 = l & 7;

    const short* gA = xb   + (size_t)mb * 65536 + lane * 8;
    const short* gB = wcat + (size_t)jb * 65536 + lane * 8;

    auto STAGE = [&](int bb, int kk) {
        const int k0 = kk << 11;          // kt*2048 shorts
        #pragma unroll
        for (int t = 0; t < 4; ++t) {
            gld_lds16(gA + k0 + t * 512, &As[bb][t << 9]);
            gld_lds16(gB + k0 + t * 512, &Bs[bb][t << 9]);
        }
    };

    STAGE(0, 0);
    STAGE(1, 1);
    asm volatile("s_waitcnt vmcnt(8)" ::: "memory");

    const f32x4 z4 = {0.f, 0.f, 0.f, 0.f};
    f32x4 acc[4][4];
    #pragma unroll
    for (int i = 0; i < 4; ++i)
        #pragma unroll
        for (int j = 0; j < 4; ++j) acc[i][j] = z4;

    // conflict-free read offsets: slot p = (((l&1)<<2)|quad) ^ ((l>>1)&7)
    const int rbase = (l >> 1) << 6;
    const int pA = (((((l & 1) << 2) | quad) ^ ((l >> 1) & 7)) << 3);
    const int rdo = rbase + pA;

    int cb = 0, sb = 2;
    #pragma unroll 1
    for (int kt = 0; kt < 32; ++kt) {
        STAGE(sb, (kt + 2) & 31);         // wrap re-stage at kt=30,31: harmless
        const short* Al = &As[cb][0];
        const short* Bl = &Bs[cb][0];
        short8 af[4], bfr[4];
        #pragma unroll
        for (int i = 0; i < 4; ++i)
            af[i] = *(const short8*)(Al + (i << 9) + rdo);
        #pragma unroll
        for (int j = 0; j < 4; ++j)
            bfr[j] = *(const short8*)(Bl + (j << 9) + rdo);
        #pragma unroll
        for (int i = 0; i < 4; ++i)
            #pragma unroll
            for (int j = 0; j < 4; ++j)
                acc[i][j] = MFMA(af[i], bfr[j], acc[i][j]);
        asm volatile("s_waitcnt vmcnt(8)" ::: "memory");
        cb = (cb == 2) ? 0 : cb + 1;
        sb = (sb == 2) ? 0 : sb + 1;
    }

    const int op = jb >> 3;               // 0=Q 1=K 2=V
    const int h  = jb & 7;                // head for this block

    if (op < 2) {
        short* dst = (op == 0) ? sp : sq;
        const float* bias = (op == 0) ? bq : bk;
        float bcol[4];
        #pragma unroll
        for (int nt = 0; nt < 4; ++nt) bcol[nt] = bias[(h << 6) + (nt << 4) + l];
        #pragma unroll
        for (int i = 0; i < 4; ++i) {
            #pragma unroll
            for (int reg = 0; reg < 4; ++reg) {
                const int r = m0 + (i << 4) + (quad << 2) + reg;
                const int b = r >> 11, s = r & 2047;
                float v[4];
                #pragma unroll
                for (int nt = 0; nt < 4; ++nt) v[nt] = acc[i][nt][reg] + bcol[nt];
                float mx = fmaxf(fmaxf(v[0], v[1]), fmaxf(v[2], v[3]));
                #pragma unroll
                for (int msk = 1; msk < 16; msk <<= 1) mx = fmaxf(mx, __shfl_xor(mx, msk));
                float e[4], ssum = 0.f;
                #pragma unroll
                for (int nt = 0; nt < 4; ++nt) { e[nt] = __expf(v[nt] - mx); ssum += e[nt]; }
                #pragma unroll
                for (int msk = 1; msk < 16; msk <<= 1) ssum += __shfl_xor(ssum, msk);
                float inv = 1.0f / ssum;
                short* o = dst + ((size_t)((b << 3) + h) * 2048 + s) * 64;
                if (op == 0) {
                    #pragma unroll
                    for (int nt = 0; nt < 4; ++nt)
                        o[(nt << 4) + l] = f2bf(sqrtf(e[nt] * inv));
                } else {
                    const int s7 = r & 7;
                    #pragma unroll
                    for (int nt = 0; nt < 4; ++nt)
                        o[((((nt << 1) + (l >> 3)) ^ s7) << 3) + l7] =
                            f2bf(sqrtf(e[nt] * inv));
                }
            }
        }
    } else {
        // V: store transposed + pi/XOR-permuted (R17, unchanged)
        float bcol[4];
        #pragma unroll
        for (int nt = 0; nt < 4; ++nt) bcol[nt] = bv[(h << 6) + (nt << 4) + l];
        #pragma unroll
        for (int i = 0; i < 4; ++i) {
            const int sb2 = m0 + (i << 4) + (quad << 2);
            const int b = sb2 >> 11, s = sb2 & 2047;
            const int gg = (s >> 2) & 15;
            const int u = ((gg >> 3) << 2) + (gg & 3);
            const int colp = (s & ~63) + (((u ^ l7)) << 3) + (((gg >> 2) & 1) << 2);
            #pragma unroll
            for (int nt = 0; nt < 4; ++nt) {
                const int d = (nt << 4) + l;
                bf16x4 pk;
                #pragma unroll
                for (int reg = 0; reg < 4; ++reg)
                    pk[reg] = f2bf(acc[i][nt][reg] + bcol[nt]);
                *(bf16x4*)(vt + ((size_t)((b << 3) + h) * 64 + d) * 2048 + colp) = pk;
            }
        }
    }
}

// ---------------------------------------------------------------------------
// Kernel 2: attention partials. Grid (32, 16, 4), 256 threads = 4 waves.
// R18: j-split x4 (8 jt per block) for occupancy. DMA-staged pre-swizzled
// K/V (R17), P-in-registers via pi-permuted vt layout, exp2 poly.
// ---------------------------------------------------------------------------
__global__ __launch_bounds__(256, 4) void attn_mfma(
    const short* __restrict__ sp, const short* __restrict__ sq,
    const short* __restrict__ vt,
    float* __restrict__ pnum, float* __restrict__ pden)
{
    __shared__ __align__(16) short sqT[2][64 * 64];   // [j][d] swizzled image
    __shared__ __align__(16) short vtT[2][64 * 64];   // [d][pi(j)] swizzled image
    const int bh = blockIdx.y;
    const int m0 = blockIdx.x << 6;
    const int z  = blockIdx.z;            // j-quarter: jt in [8z, 8z+8)
    const int tid = threadIdx.x;
    const int w = tid >> 6, lane = tid & 63;
    const int l = lane & 15, quad = lane >> 4;
    const int l7 = l & 7;

    const short* spB = sp + (size_t)bh * 2048 * 64;
    const short* sqB = sq + (size_t)bh * 2048 * 64;
    const short* vtB = vt + (size_t)bh * 64 * 2048;

    // persistent sp frags (B-operand), negated: MFMA(sq,-sp,1) = 1-bc = u
    const short* apr = spB + (size_t)(m0 + w * 16 + l) * 64 + quad * 8;
    short8 nq0 = (*(const short8*)(apr)) ^ (short)0x8000;
    short8 nq1 = (*(const short8*)(apr + 32)) ^ (short)0x8000;

    // DMA staging: call r covers rows 8r..8r+7 (1KB); lane -> row 8r+(lane>>3),
    // 16B unit (lane&7). Wave w owns calls {2w, 2w+1} of each tile.
    const int lr = lane >> 3;
    const int lu = lane & 7;
    const int r0 = w << 1;

    auto STAGEATT = [&](int buf, int jrow) {
        #pragma unroll
        for (int k = 0; k < 2; ++k) {
            const int r = r0 + k;
            gld_lds16(sqB + (size_t)(jrow + (r << 3) + lr) * 64 + (lu << 3),
                      &sqT[buf][r << 9]);
            gld_lds16(vtB + (size_t)((r << 3) + lr) * 2048 + jrow + (lu << 3),
                      &vtT[buf][r << 9]);
        }
    };

    // reader slot offset: rows read are (16*k + l) so row&7 == l7 everywhere
    const int sRd = (quad ^ l7) << 3;     // 16B-slot quad; ^32 -> slot quad+4

    // prologue: stage jt = 8z into buffer 0
    STAGEATT(0, z << 9);
    __syncthreads();

    const f32x4 ones4 = {1.f, 1.f, 1.f, 1.f};
    const f32x4 z4 = {0.f, 0.f, 0.f, 0.f};
    f32x4 acc[4] = {z4, z4, z4, z4};
    f32x2 den2 = {0.f, 0.f};

    #pragma unroll 1
    for (int jtl = 0; jtl < 8; ++jtl) {
        const int cb = jtl & 1, nb = cb ^ 1;
        const int j0n = ((z << 3) + ((jtl + 1) & 7)) << 6;  // wrap: harmless
        STAGEATT(nb, j0n);   // DMA into the buffer not read this iteration

        // QK^T transposed: lane l = Q-row, 16nt+4q+reg = j-local; u = 1-bc
        uint2 pk[4];
        const short* sqL = &sqT[cb][0];
        #pragma unroll
        for (int nt = 0; nt < 4; ++nt) {
            const short* ar = sqL + ((nt * 16 + l) << 6);
            short8 sa0 = *(const short8*)(ar + sRd);
            short8 sa1 = *(const short8*)(ar + (sRd ^ 32));
            f32x4 p = MFMA(sa0, nq0, ones4);
            p = MFMA(sa1, nq1, p);
            // w = u * poly(u), coefficients pre-scaled by -log2(e)
            f32x2 u01 = {p[0], p[1]};
            f32x2 u23 = {p[2], p[3]};
            const f32x2 zz = {0.f, 0.f};
#if __has_builtin(__builtin_elementwise_max)
            u01 = __builtin_elementwise_max(u01, zz);
            u23 = __builtin_elementwise_max(u23, zz);
#else
            u01.x = fmaxf(u01.x, 0.f); u01.y = fmaxf(u01.y, 0.f);
            u23.x = fmaxf(u23.x, 0.f); u23.y = fmaxf(u23.y, 0.f);
#endif
            f32x2 t01 = {-0.00133017f, -0.00133017f};
            f32x2 t23 = t01;
            t01 = t01 * u01 - 0.00219618f;  t23 = t23 * u23 - 0.00219618f;
            t01 = t01 * u01 - 0.00555151f;  t23 = t23 * u23 - 0.00555151f;
            t01 = t01 * u01 - 0.01465597f;  t23 = t23 * u23 - 0.01465597f;
            t01 = t01 * u01 - 0.04121986f;  t23 = t23 * u23 - 0.04121986f;
            t01 = t01 * u01 - 0.12823956f;  t23 = t23 * u23 - 0.12823956f;
            t01 = t01 * u01 - 0.48089834f;  t23 = t23 * u23 - 0.48089834f;
            t01 = t01 * u01 - 2.88539008f;  t23 = t23 * u23 - 2.88539008f;
            f32x2 w01 = u01 * t01;          // <= 0
            f32x2 w23 = u23 * t23;
#if __has_builtin(__builtin_amdgcn_exp2f)
            float e0 = __builtin_amdgcn_exp2f(w01.x);
            float e1 = __builtin_amdgcn_exp2f(w01.y);
            float e2 = __builtin_amdgcn_exp2f(w23.x);
            float e3 = __builtin_amdgcn_exp2f(w23.y);
#else
            float e0 = exp2f(w01.x), e1 = exp2f(w01.y);
            float e2 = exp2f(w23.x), e3 = exp2f(w23.y);
#endif
            f32x2 es = {e0 + e2, e1 + e3};
            den2 += es;
            pk[nt].x = (__float_as_uint(e0) >> 16) | (__float_as_uint(e1) & 0xffff0000u);
            pk[nt].y = (__float_as_uint(e2) >> 16) | (__float_as_uint(e3) & 0xffff0000u);
        }

        // PV: pk registers ARE the A-frags (j-order matched by vt layout)
        u32x4 c0; c0.x = pk[0].x; c0.y = pk[0].y; c0.z = pk[1].x; c0.w = pk[1].y;
        u32x4 c1; c1.x = pk[2].x; c1.y = pk[2].y; c1.z = pk[3].x; c1.w = pk[3].y;
        short8 pa0 = __builtin_bit_cast(short8, c0);
        short8 pa1 = __builtin_bit_cast(short8, c1);
        const short* vL = &vtT[cb][0];
        #pragma unroll
        for (int t4 = 0; t4 < 4; ++t4) {
            const short* vr = vL + ((t4 * 16 + l) << 6);
            short8 vb0 = *(const short8*)(vr + sRd);
            short8 vb1 = *(const short8*)(vr + (sRd ^ 32));
            acc[t4] = MFMA(pa0, vb0, acc[t4]);
            acc[t4] = MFMA(pa1, vb1, acc[t4]);
        }

        // barrier: compiler drains vmcnt(0) -> DMA for nb has landed
        __syncthreads();
    }

    // den: sum across quads (each quad covered different j); lane<16 stores
    float den = den2.x + den2.y;
    den += __shfl_xor(den, 16);
    den += __shfl_xor(den, 32);
    if (lane < 16)
        pden[(size_t)z * 32768 + bh * 2048 + m0 + w * 16 + l] = den;

    // partial numerator, f32, no division
    const int b = bh >> 3, hh = bh & 7;
    float* np = pnum + (size_t)z * 4096 * 512;
    #pragma unroll
    for (int t4 = 0; t4 < 4; ++t4)
        #pragma unroll
        for (int reg = 0; reg < 4; ++reg) {
            const int row = m0 + w * 16 + quad * 4 + reg;
            np[((size_t)(b * 2048 + row)) * 512 + hh * 64 + t4 * 16 + l] =
                acc[t4][reg];
        }
}

// ---------------------------------------------------------------------------
// Kernel 2b: combine 4 quarters -> attB bf16 (swizzle-packed for out_mfma).
// ---------------------------------------------------------------------------
__global__ __launch_bounds__(256) void combine_attn(
    const float* __restrict__ pnum, const float* __restrict__ pden,
    short* __restrict__ attB)
{
    const int idx = (blockIdx.x * 256 + threadIdx.x) << 3;
    const int r = idx >> 9;               // 0..4095
    const int c = idx & 511;
    const int hh = c >> 6;
    const int bh = ((r >> 11) << 3) + hh;
    const int srow = r & 2047;
    float d = 0.f;
    #pragma unroll
    for (int zi = 0; zi < 4; ++zi)
        d += pden[(size_t)zi * 32768 + bh * 2048 + srow];
    const float inv = 1.0f / d;
    float4 a0 = {0.f, 0.f, 0.f, 0.f}, a1 = {0.f, 0.f, 0.f, 0.f};
    #pragma unroll
    for (int zi = 0; zi < 4; ++zi) {
        const float* n0 = pnum + (size_t)zi * 4096 * 512 + (size_t)r * 512 + c;
        float4 b0 = *(const float4*)(n0);
        float4 b1 = *(const float4*)(n0 + 4);
        a0.x += b0.x; a0.y += b0.y; a0.z += b0.z; a0.w += b0.w;
        a1.x += b1.x; a1.y += b1.y; a1.z += b1.z; a1.w += b1.w;
    }
    short8 o;
    o[0] = f2bf(a0.x * inv); o[1] = f2bf(a0.y * inv);
    o[2] = f2bf(a0.z * inv); o[3] = f2bf(a0.w * inv);
    o[4] = f2bf(a1.x * inv); o[5] = f2bf(a1.y * inv);
    o[6] = f2bf(a1.z * inv); o[7] = f2bf(a1.w * inv);
    // swizzle-packed dst: [mb][kt][r'][p] (K=512 -> 16 kt per mb)
    const int mb = r >> 6, rm = r & 63;
    const int kt = c >> 5, u = (c >> 3) & 3;
    const int rp = rm >> 1;
    const int up = ((rm & 1) << 2) | u;
    const int p  = up ^ (rp & 7);
    *(short8*)(attB + ((size_t)(mb * 16 + kt)) * 2048 + rp * 64 + p * 8) = o;
}

// ---------------------------------------------------------------------------
// Kernel 3: out = attB @ Wo + bo -> fp32. Grid (16, 64), single wave,
// triple-buffer vmcnt(8). R18: swizzle-packed attB/wot -> conflict-free.
// ---------------------------------------------------------------------------
__global__ __launch_bounds__(64) void out_mfma(
    const short* __restrict__ attB, const short* __restrict__ wot,
    const float* __restrict__ bo, float* __restrict__ out)
{
    __shared__ short As[3][64 * 32];      // 4KB per buffer
    __shared__ short Bs[3][64 * 32];
    const int nb = blockIdx.x;            // 0..15 (64-col tile)
    const int mb = blockIdx.y;            // 0..63
    const int n0 = nb << 6;
    const int m0 = mb << 6;
    const int lane = threadIdx.x;
    const int l = lane & 15, quad = lane >> 4;

    const short* gA = attB + (size_t)mb * 32768 + lane * 8;
    const short* gB = wot  + (size_t)nb * 32768 + lane * 8;

    auto STAGE = [&](int bb, int kk) {
        const int k0 = kk << 11;
        #pragma unroll
        for (int t = 0; t < 4; ++t) {
            gld_lds16(gA + k0 + t * 512, &As[bb][t << 9]);
            gld_lds16(gB + k0 + t * 512, &Bs[bb][t << 9]);
        }
    };

    STAGE(0, 0);
    STAGE(1, 1);
    asm volatile("s_waitcnt vmcnt(8)" ::: "memory");

    const f32x4 z4 = {0.f, 0.f, 0.f, 0.f};
    f32x4 acc[4][4];
    #pragma unroll
    for (int i = 0; i < 4; ++i)
        #pragma unroll
        for (int j = 0; j < 4; ++j) acc[i][j] = z4;

    const int rbase = (l >> 1) << 6;
    const int pA = (((((l & 1) << 2) | quad) ^ ((l >> 1) & 7)) << 3);
    const int rdo = rbase + pA;

    int cb = 0, sb = 2;
    #pragma unroll 1
    for (int kt = 0; kt < 16; ++kt) {
        STAGE(sb, (kt + 2) & 15);         // wrap re-stage at kt=14,15: harmless
        const short* Al = &As[cb][0];
        const short* Bl = &Bs[cb][0];
        short8 af[4], bfr[4];
        #pragma unroll
        for (int i = 0; i < 4; ++i)
            af[i] = *(const short8*)(Al + (i << 9) + rdo);
        #pragma unroll
        for (int j = 0; j < 4; ++j)
            bfr[j] = *(const short8*)(Bl + (j << 9) + rdo);
        #pragma unroll
        for (int i = 0; i < 4; ++i)
            #pragma unroll
            for (int j = 0; j < 4; ++j)
                acc[i][j] = MFMA(af[i], bfr[j], acc[i][j]);
        asm volatile("s_waitcnt vmcnt(8)" ::: "memory");
        cb = (cb == 2) ? 0 : cb + 1;
        sb = (sb == 2) ? 0 : sb + 1;
    }

    float bcol[4];
    #pragma unroll
    for (int nt = 0; nt < 4; ++nt) bcol[nt] = bo[n0 + (nt << 4) + l];
    #pragma unroll
    for (int i = 0; i < 4; ++i)
        #pragma unroll
        for (int reg = 0; reg < 4; ++reg) {
            const int m = m0 + (i << 4) + (quad << 2) + reg;
            float* o = out + (size_t)m * 1024 + n0 + l;
            #pragma unroll
            for (int nt = 0; nt < 4; ++nt)
                o[nt << 4] = acc[i][nt][reg] + bcol[nt];
        }
}

// ---------------------------------------------------------------------------
extern "C" void kernel_launch(void* const* d_in, const int* in_sizes, int n_in,
                              void* d_out, int out_size, void* d_ws, size_t ws_size,
                              hipStream_t stream) {
    const float* xr = (const float*)d_in[0];
    const float* xi = (const float*)d_in[1];
    const float* Wq = (const float*)d_in[2];
    const float* bq = (const float*)d_in[3];
    const float* Wk = (const float*)d_in[4];
    const float* bk = (const float*)d_in[5];
    const float* Wv = (const float*)d_in[6];
    const float* bv = (const float*)d_in[7];
    const float* Wo = (const float*)d_in[8];
    const float* bo = (const float*)d_in[9];
    float* out = (float*)d_out;

    short* base = (short*)d_ws;
    short* xb   = base;                      // 4096*1024 swizzle-packed
    short* wqt  = xb  + 4194304;             // wcat: 3 x 512*1024 packed
    short* wot  = wqt + 1572864;             // 1024*512 packed
    short* spW  = wot + 524288;              // 16*2048*64 linear
    short* sqW  = spW + 2097152;             // pre-swizzled (R17)
    short* vtW  = sqW + 2097152;             // [b,h,d,s] pi+XOR (R17)
    short* attB = vtW + 2097152;             // 4096*512 swizzle-packed
    float* pnum = (float*)(attB + 2097152);  // 4 x 4096*512 f32 = 32MB
    float* pden = pnum + 4 * 2097152;        // 4 x 16*2048 f32
    // total ~= 28MB + 32MB + 0.5MB ~= 60.5MB

    hipLaunchKernelGGL(prep_all, dim3(4096), dim3(256), 0, stream,
                       xr, xi, xb, Wq, Wk, Wv, Wo, wqt, wot);
    hipLaunchKernelGGL(qkv_mfma, dim3(24, 64), dim3(64), 0, stream,
                       xb, wqt, bq, bk, bv, spW, sqW, vtW);
    hipLaunchKernelGGL(attn_mfma, dim3(32, 16, 4), dim3(256), 0, stream,
                       spW, sqW, vtW, pnum, pden);
    hipLaunchKernelGGL(combine_attn, dim3(1024), dim3(256), 0, stream,
                       pnum, pden, attB);
    hipLaunchKernelGGL(out_mfma, dim3(16, 64), dim3(64), 0, stream,
                       attB, wot, bo, out);
}

// Round 11
// 182.754 us; speedup vs baseline: 1.1139x; 1.0085x over previous
//
#include <hip/hip_runtime.h>
#include <math.h>

// GeoAttention on gfx950: B=2, S=2048, DIM=512, H=8, HD=64.
// bf16 MFMA (16x16x32) everywhere, fp32 accumulate.
// R19: attn Q-block 64 -> 128 rows (each wave owns TWO 16-row strips).
// R18's j-split x4 was a null (43.6us, occupancy 29%): more blocks just
// duplicated per-block fixed costs; the per-jt barrier overhead fraction
// was unchanged. Now per jt each wave runs 32 MFMA + 2x poly between
// barriers (2x compute per barrier/stage), and the K/V LDS fragments are
// SHARED between strips (each ds_read feeds 2 MFMAs). K/V global re-reads
// halve (16 Q-tiles). Grid (16,16,4) = 1024 blocks = 4/CU, all co-resident
// under the 5-block LDS cap (single dispatch round).
// qkv/out (R18 swizzle-packed, conflict-free), prep_all, combine unchanged.

typedef __attribute__((ext_vector_type(8))) short short8;
typedef __attribute__((ext_vector_type(4))) short bf16x4;
typedef __attribute__((ext_vector_type(4))) float f32x4;
typedef __attribute__((ext_vector_type(2))) float f32x2;
typedef __attribute__((ext_vector_type(4))) unsigned int u32x4;

#define MFMA(a, b, c) __builtin_amdgcn_mfma_f32_16x16x32_bf16((a), (b), (c), 0, 0, 0)

static __device__ __forceinline__ short f2bf(float f) {
    unsigned u = __float_as_uint(f);
    u += 0x7fffu + ((u >> 16) & 1u);          // round-to-nearest-even
    return (short)(u >> 16);
}

// global -> LDS direct DMA, 16B per lane, wave-uniform LDS base + lane*16
static __device__ __forceinline__ void gld_lds16(const short* g, short* l) {
    __builtin_amdgcn_global_load_lds(
        (const __attribute__((address_space(1))) unsigned int*)g,
        (__attribute__((address_space(3))) unsigned int*)l, 16, 0, 0);
}

// ---------------------------------------------------------------------------
// Prep: xb (swizzle-packed) + weight transposes (wcat/wot swizzle-packed).
// Swizzle-packed [NB][KT][32 r'][8 p][8] layout for a [64r][32k]-short tile:
//   r' = r>>1, u' = ((r&1)<<2)|(unit u = (k>>3)&3), p = u' ^ (r'&7).
// ---------------------------------------------------------------------------
__global__ __launch_bounds__(256) void prep_all(
    const float* __restrict__ xr, const float* __restrict__ xi,
    short* __restrict__ xb,
    const float* __restrict__ Wq, const float* __restrict__ Wk,
    const float* __restrict__ Wv, const float* __restrict__ Wo,
    short* __restrict__ wqt, short* __restrict__ wot)
{
    const int bid = blockIdx.x;
    if (bid < 2048) {
        const unsigned wid = bid * 256 + threadIdx.x;   // dst = xb + wid*8
        const int p  = wid & 7;
        const int rp = (wid >> 3) & 31;
        const int kt = (wid >> 8) & 31;
        const int mb = wid >> 13;
        const int up = p ^ (rp & 7);
        const int m  = (mb << 6) | (rp << 1) | (up >> 2);
        const int k  = (kt << 5) | ((up & 3) << 3);
        const float* s = (k < 512) ? (xr + (size_t)m * 512 + k)
                                   : (xi + (size_t)m * 512 + (k - 512));
        float4 t0 = *(const float4*)(s);
        float4 t1 = *(const float4*)(s + 4);
        short8 o;
        o[0] = f2bf(t0.x); o[1] = f2bf(t0.y); o[2] = f2bf(t0.z); o[3] = f2bf(t0.w);
        o[4] = f2bf(t1.x); o[5] = f2bf(t1.y); o[6] = f2bf(t1.z); o[7] = f2bf(t1.w);
        *(short8*)(xb + (size_t)wid * 8) = o;
    } else {
        __shared__ float tt[32][33];
        const int t = bid - 2048;
        const int z = t >> 9;
        const int idx = t & 511;
        const float* src = (z == 0) ? Wq : (z == 1) ? Wk : (z == 2) ? Wv : Wo;
        const int N = (z < 3) ? 512 : 1024;
        const int bx = (z < 3) ? (idx & 15) : (idx & 31);
        const int by = (z < 3) ? (idx >> 4) : (idx >> 5);
        const int n0 = bx << 5, k0 = by << 5;
        const int tx = threadIdx.x & 31, ty = threadIdx.x >> 5;
        #pragma unroll
        for (int i = 0; i < 4; ++i)
            tt[ty + 8 * i][tx] = src[(size_t)(k0 + ty + 8 * i) * N + n0 + tx];
        __syncthreads();
        const int k = k0 + tx;
        const int kt = k >> 5, u = (k >> 3) & 3, off = k & 7;
        #pragma unroll
        for (int i = 0; i < 4; ++i) {
            const int n = n0 + ty + 8 * i;
            const int nb = n >> 6, rn = n & 63;
            const int rp = rn >> 1;
            const int up = ((rn & 1) << 2) | u;
            const int p  = up ^ (rp & 7);
            const float v = tt[tx][ty + 8 * i];
            if (z < 3)
                wqt[(size_t)z * 524288 +
                    ((size_t)(nb * 32 + kt)) * 2048 + rp * 64 + p * 8 + off] = f2bf(v);
            else
                wot[((size_t)(nb * 16 + kt)) * 2048 + rp * 64 + p * 8 + off] = f2bf(v);
        }
    }
}

// ---------------------------------------------------------------------------
// Kernel 1: QKV projection. Grid (24, 64), 64 threads = ONE wave, no barrier.
// Wave-private 64x64 tile, K=1024 (32 steps), triple-buffer, distance 2,
// vmcnt(8). Swizzle-packed xb/wcat -> linear DMA + conflict-free reads.
// Epilogue: sq stored XOR-pre-swizzled, vt stored pi+XOR-permuted.
// ---------------------------------------------------------------------------
__global__ __launch_bounds__(64) void qkv_mfma(
    const short* __restrict__ xb, const short* __restrict__ wcat,
    const float* __restrict__ bq, const float* __restrict__ bk,
    const float* __restrict__ bv,
    short* __restrict__ sp, short* __restrict__ sq, short* __restrict__ vt)
{
    __shared__ short As[3][64 * 32];      // 4KB per buffer (32 r' x 128B)
    __shared__ short Bs[3][64 * 32];
    const int jb = blockIdx.x;            // 0..23
    const int mb = blockIdx.y;            // 0..63
    const int m0 = mb << 6;
    const int lane = threadIdx.x;
    const int l = lane & 15, quad = lane >> 4;
    const int l7 = l & 7;

    const short* gA = xb   + (size_t)mb * 65536 + lane * 8;
    const short* gB = wcat + (size_t)jb * 65536 + lane * 8;

    auto STAGE = [&](int bb, int kk) {
        const int k0 = kk << 11;          // kt*2048 shorts
        #pragma unroll
        for (int t = 0; t < 4; ++t) {
            gld_lds16(gA + k0 + t * 512, &As[bb][t << 9]);
            gld_lds16(gB + k0 + t * 512, &Bs[bb][t << 9]);
        }
    };

    STAGE(0, 0);
    STAGE(1, 1);
    asm volatile("s_waitcnt vmcnt(8)" ::: "memory");

    const f32x4 z4 = {0.f, 0.f, 0.f, 0.f};
    f32x4 acc[4][4];
    #pragma unroll
    for (int i = 0; i < 4; ++i)
        #pragma unroll
        for (int j = 0; j < 4; ++j) acc[i][j] = z4;

    // conflict-free read offsets: slot p = (((l&1)<<2)|quad) ^ ((l>>1)&7)
    const int rbase = (l >> 1) << 6;
    const int pA = (((((l & 1) << 2) | quad) ^ ((l >> 1) & 7)) << 3);
    const int rdo = rbase + pA;

    int cb = 0, sb = 2;
    #pragma unroll 1
    for (int kt = 0; kt < 32; ++kt) {
        STAGE(sb, (kt + 2) & 31);         // wrap re-stage at kt=30,31: harmless
        const short* Al = &As[cb][0];
        const short* Bl = &Bs[cb][0];
        short8 af[4], bfr[4];
        #pragma unroll
        for (int i = 0; i < 4; ++i)
            af[i] = *(const short8*)(Al + (i << 9) + rdo);
        #pragma unroll
        for (int j = 0; j < 4; ++j)
            bfr[j] = *(const short8*)(Bl + (j << 9) + rdo);
        #pragma unroll
        for (int i = 0; i < 4; ++i)
            #pragma unroll
            for (int j = 0; j < 4; ++j)
                acc[i][j] = MFMA(af[i], bfr[j], acc[i][j]);
        asm volatile("s_waitcnt vmcnt(8)" ::: "memory");
        cb = (cb == 2) ? 0 : cb + 1;
        sb = (sb == 2) ? 0 : sb + 1;
    }

    const int op = jb >> 3;               // 0=Q 1=K 2=V
    const int h  = jb & 7;                // head for this block

    if (op < 2) {
        short* dst = (op == 0) ? sp : sq;
        const float* bias = (op == 0) ? bq : bk;
        float bcol[4];
        #pragma unroll
        for (int nt = 0; nt < 4; ++nt) bcol[nt] = bias[(h << 6) + (nt << 4) + l];
        #pragma unroll
        for (int i = 0; i < 4; ++i) {
            #pragma unroll
            for (int reg = 0; reg < 4; ++reg) {
                const int r = m0 + (i << 4) + (quad << 2) + reg;
                const int b = r >> 11, s = r & 2047;
                float v[4];
                #pragma unroll
                for (int nt = 0; nt < 4; ++nt) v[nt] = acc[i][nt][reg] + bcol[nt];
                float mx = fmaxf(fmaxf(v[0], v[1]), fmaxf(v[2], v[3]));
                #pragma unroll
                for (int msk = 1; msk < 16; msk <<= 1) mx = fmaxf(mx, __shfl_xor(mx, msk));
                float e[4], ssum = 0.f;
                #pragma unroll
                for (int nt = 0; nt < 4; ++nt) { e[nt] = __expf(v[nt] - mx); ssum += e[nt]; }
                #pragma unroll
                for (int msk = 1; msk < 16; msk <<= 1) ssum += __shfl_xor(ssum, msk);
                float inv = 1.0f / ssum;
                short* o = dst + ((size_t)((b << 3) + h) * 2048 + s) * 64;
                if (op == 0) {
                    #pragma unroll
                    for (int nt = 0; nt < 4; ++nt)
                        o[(nt << 4) + l] = f2bf(sqrtf(e[nt] * inv));
                } else {
                    const int s7 = r & 7;
                    #pragma unroll
                    for (int nt = 0; nt < 4; ++nt)
                        o[((((nt << 1) + (l >> 3)) ^ s7) << 3) + l7] =
                            f2bf(sqrtf(e[nt] * inv));
                }
            }
        }
    } else {
        // V: store transposed + pi/XOR-permuted
        float bcol[4];
        #pragma unroll
        for (int nt = 0; nt < 4; ++nt) bcol[nt] = bv[(h << 6) + (nt << 4) + l];
        #pragma unroll
        for (int i = 0; i < 4; ++i) {
            const int sb2 = m0 + (i << 4) + (quad << 2);
            const int b = sb2 >> 11, s = sb2 & 2047;
            const int gg = (s >> 2) & 15;
            const int u = ((gg >> 3) << 2) + (gg & 3);
            const int colp = (s & ~63) + (((u ^ l7)) << 3) + (((gg >> 2) & 1) << 2);
            #pragma unroll
            for (int nt = 0; nt < 4; ++nt) {
                const int d = (nt << 4) + l;
                bf16x4 pk;
                #pragma unroll
                for (int reg = 0; reg < 4; ++reg)
                    pk[reg] = f2bf(acc[i][nt][reg] + bcol[nt]);
                *(bf16x4*)(vt + ((size_t)((b << 3) + h) * 64 + d) * 2048 + colp) = pk;
            }
        }
    }
}

// ---------------------------------------------------------------------------
// Kernel 2: attention partials. Grid (16, 16, 4), 256 threads = 4 waves.
// R19: 128 Q-rows per block; wave w owns strips [m0+16w,+16) and
// [m0+64+16w,+16). K/V LDS fragments shared between strips (1 ds_read ->
// 2 MFMAs). DMA-staged pre-swizzled K/V, P-in-registers, exp2 poly.
// ---------------------------------------------------------------------------
__global__ __launch_bounds__(256, 4) void attn_mfma(
    const short* __restrict__ sp, const short* __restrict__ sq,
    const short* __restrict__ vt,
    float* __restrict__ pnum, float* __restrict__ pden)
{
    __shared__ __align__(16) short sqT[2][64 * 64];   // [j][d] swizzled image
    __shared__ __align__(16) short vtT[2][64 * 64];   // [d][pi(j)] swizzled image
    const int bh = blockIdx.y;
    const int m0 = blockIdx.x << 7;       // 128-row Q tile
    const int z  = blockIdx.z;            // j-quarter: jt in [8z, 8z+8)
    const int tid = threadIdx.x;
    const int w = tid >> 6, lane = tid & 63;
    const int l = lane & 15, quad = lane >> 4;
    const int l7 = l & 7;

    const short* spB = sp + (size_t)bh * 2048 * 64;
    const short* sqB = sq + (size_t)bh * 2048 * 64;
    const short* vtB = vt + (size_t)bh * 64 * 2048;

    // persistent sp frags for both strips, negated: MFMA(sq,-sp,1) = 1-bc
    const short* apr0 = spB + (size_t)(m0 + w * 16 + l) * 64 + quad * 8;
    const short* apr1 = apr0 + (size_t)64 * 64;       // +64 rows
    short8 nqa0 = (*(const short8*)(apr0)) ^ (short)0x8000;
    short8 nqa1 = (*(const short8*)(apr0 + 32)) ^ (short)0x8000;
    short8 nqb0 = (*(const short8*)(apr1)) ^ (short)0x8000;
    short8 nqb1 = (*(const short8*)(apr1 + 32)) ^ (short)0x8000;

    // DMA staging: call r covers rows 8r..8r+7 (1KB); lane -> row 8r+(lane>>3),
    // 16B unit (lane&7). Wave w owns calls {2w, 2w+1} of each tile.
    const int lr = lane >> 3;
    const int lu = lane & 7;
    const int r0 = w << 1;

    auto STAGEATT = [&](int buf, int jrow) {
        #pragma unroll
        for (int k = 0; k < 2; ++k) {
            const int r = r0 + k;
            gld_lds16(sqB + (size_t)(jrow + (r << 3) + lr) * 64 + (lu << 3),
                      &sqT[buf][r << 9]);
            gld_lds16(vtB + (size_t)((r << 3) + lr) * 2048 + jrow + (lu << 3),
                      &vtT[buf][r << 9]);
        }
    };

    // reader slot offset: rows read are (16*k + l) so row&7 == l7 everywhere
    const int sRd = (quad ^ l7) << 3;     // 16B-slot quad; ^32 -> slot quad+4

    // prologue: stage jt = 8z into buffer 0
    STAGEATT(0, z << 9);
    __syncthreads();

    const f32x4 ones4 = {1.f, 1.f, 1.f, 1.f};
    const f32x4 z4 = {0.f, 0.f, 0.f, 0.f};
    f32x4 accA[4] = {z4, z4, z4, z4};
    f32x4 accB[4] = {z4, z4, z4, z4};
    f32x2 denA = {0.f, 0.f}, denB = {0.f, 0.f};

    // score transform: u -> exp2(u * poly(u)) packed as 4 bf16; den += e
    auto SCORE = [&](const f32x4& p, f32x2& dacc) -> uint2 {
        f32x2 u01 = {p[0], p[1]};
        f32x2 u23 = {p[2], p[3]};
        const f32x2 zz = {0.f, 0.f};
#if __has_builtin(__builtin_elementwise_max)
        u01 = __builtin_elementwise_max(u01, zz);
        u23 = __builtin_elementwise_max(u23, zz);
#else
        u01.x = fmaxf(u01.x, 0.f); u01.y = fmaxf(u01.y, 0.f);
        u23.x = fmaxf(u23.x, 0.f); u23.y = fmaxf(u23.y, 0.f);
#endif
        f32x2 t01 = {-0.00133017f, -0.00133017f};
        f32x2 t23 = t01;
        t01 = t01 * u01 - 0.00219618f;  t23 = t23 * u23 - 0.00219618f;
        t01 = t01 * u01 - 0.00555151f;  t23 = t23 * u23 - 0.00555151f;
        t01 = t01 * u01 - 0.01465597f;  t23 = t23 * u23 - 0.01465597f;
        t01 = t01 * u01 - 0.04121986f;  t23 = t23 * u23 - 0.04121986f;
        t01 = t01 * u01 - 0.12823956f;  t23 = t23 * u23 - 0.12823956f;
        t01 = t01 * u01 - 0.48089834f;  t23 = t23 * u23 - 0.48089834f;
        t01 = t01 * u01 - 2.88539008f;  t23 = t23 * u23 - 2.88539008f;
        f32x2 w01 = u01 * t01;          // <= 0
        f32x2 w23 = u23 * t23;
#if __has_builtin(__builtin_amdgcn_exp2f)
        float e0 = __builtin_amdgcn_exp2f(w01.x);
        float e1 = __builtin_amdgcn_exp2f(w01.y);
        float e2 = __builtin_amdgcn_exp2f(w23.x);
        float e3 = __builtin_amdgcn_exp2f(w23.y);
#else
        float e0 = exp2f(w01.x), e1 = exp2f(w01.y);
        float e2 = exp2f(w23.x), e3 = exp2f(w23.y);
#endif
        f32x2 es = {e0 + e2, e1 + e3};
        dacc += es;
        uint2 r;
        r.x = (__float_as_uint(e0) >> 16) | (__float_as_uint(e1) & 0xffff0000u);
        r.y = (__float_as_uint(e2) >> 16) | (__float_as_uint(e3) & 0xffff0000u);
        return r;
    };

    #pragma unroll 1
    for (int jtl = 0; jtl < 8; ++jtl) {
        const int cb = jtl & 1, nb = cb ^ 1;
        const int j0n = ((z << 3) + ((jtl + 1) & 7)) << 6;  // wrap: harmless
        STAGEATT(nb, j0n);   // DMA into the buffer not read this iteration

        // QK^T transposed, both strips sharing sq fragments
        uint2 pkA[4], pkB[4];
        const short* sqL = &sqT[cb][0];
        #pragma unroll
        for (int nt = 0; nt < 4; ++nt) {
            const short* ar = sqL + ((nt * 16 + l) << 6);
            short8 sa0 = *(const short8*)(ar + sRd);
            short8 sa1 = *(const short8*)(ar + (sRd ^ 32));
            f32x4 pA = MFMA(sa0, nqa0, ones4);
            pA = MFMA(sa1, nqa1, pA);
            f32x4 pB = MFMA(sa0, nqb0, ones4);
            pB = MFMA(sa1, nqb1, pB);
            pkA[nt] = SCORE(pA, denA);
            pkB[nt] = SCORE(pB, denB);
        }

        // PV: pk registers ARE the A-frags; V fragments shared between strips
        u32x4 cA0; cA0.x = pkA[0].x; cA0.y = pkA[0].y; cA0.z = pkA[1].x; cA0.w = pkA[1].y;
        u32x4 cA1; cA1.x = pkA[2].x; cA1.y = pkA[2].y; cA1.z = pkA[3].x; cA1.w = pkA[3].y;
        u32x4 cB0; cB0.x = pkB[0].x; cB0.y = pkB[0].y; cB0.z = pkB[1].x; cB0.w = pkB[1].y;
        u32x4 cB1; cB1.x = pkB[2].x; cB1.y = pkB[2].y; cB1.z = pkB[3].x; cB1.w = pkB[3].y;
        short8 paA0 = __builtin_bit_cast(short8, cA0);
        short8 paA1 = __builtin_bit_cast(short8, cA1);
        short8 paB0 = __builtin_bit_cast(short8, cB0);
        short8 paB1 = __builtin_bit_cast(short8, cB1);
        const short* vL = &vtT[cb][0];
        #pragma unroll
        for (int t4 = 0; t4 < 4; ++t4) {
            const short* vr = vL + ((t4 * 16 + l) << 6);
            short8 vb0 = *(const short8*)(vr + sRd);
            short8 vb1 = *(const short8*)(vr + (sRd ^ 32));
            accA[t4] = MFMA(paA0, vb0, accA[t4]);
            accA[t4] = MFMA(paA1, vb1, accA[t4]);
            accB[t4] = MFMA(paB0, vb0, accB[t4]);
            accB[t4] = MFMA(paB1, vb1, accB[t4]);
        }

        // barrier: compiler drains vmcnt(0) -> DMA for nb has landed
        __syncthreads();
    }

    // den: sum across quads (each quad covered different j); lane<16 stores
    float dA = denA.x + denA.y;
    dA += __shfl_xor(dA, 16);
    dA += __shfl_xor(dA, 32);
    float dB = denB.x + denB.y;
    dB += __shfl_xor(dB, 16);
    dB += __shfl_xor(dB, 32);
    if (lane < 16) {
        pden[(size_t)z * 32768 + bh * 2048 + m0 + w * 16 + l] = dA;
        pden[(size_t)z * 32768 + bh * 2048 + m0 + 64 + w * 16 + l] = dB;
    }

    // partial numerators, f32, no division
    const int b = bh >> 3, hh = bh & 7;
    float* np = pnum + (size_t)z * 4096 * 512;
    #pragma unroll
    for (int t4 = 0; t4 < 4; ++t4)
        #pragma unroll
        for (int reg = 0; reg < 4; ++reg) {
            const int rowA = m0 + w * 16 + quad * 4 + reg;
            np[((size_t)(b * 2048 + rowA)) * 512 + hh * 64 + t4 * 16 + l] =
                accA[t4][reg];
            np[((size_t)(b * 2048 + rowA + 64)) * 512 + hh * 64 + t4 * 16 + l] =
                accB[t4][reg];
        }
}

// ---------------------------------------------------------------------------
// Kernel 2b: combine 4 quarters -> attB bf16 (swizzle-packed for out_mfma).
// ---------------------------------------------------------------------------
__global__ __launch_bounds__(256) void combine_attn(
    const float* __restrict__ pnum, const float* __restrict__ pden,
    short* __restrict__ attB)
{
    const int idx = (blockIdx.x * 256 + threadIdx.x) << 3;
    const int r = idx >> 9;               // 0..4095
    const int c = idx & 511;
    const int hh = c >> 6;
    const int bh = ((r >> 11) << 3) + hh;
    const int srow = r & 2047;
    float d = 0.f;
    #pragma unroll
    for (int zi = 0; zi < 4; ++zi)
        d += pden[(size_t)zi * 32768 + bh * 2048 + srow];
    const float inv = 1.0f / d;
    float4 a0 = {0.f, 0.f, 0.f, 0.f}, a1 = {0.f, 0.f, 0.f, 0.f};
    #pragma unroll
    for (int zi = 0; zi < 4; ++zi) {
        const float* n0 = pnum + (size_t)zi * 4096 * 512 + (size_t)r * 512 + c;
        float4 b0 = *(const float4*)(n0);
        float4 b1 = *(const float4*)(n0 + 4);
        a0.x += b0.x; a0.y += b0.y; a0.z += b0.z; a0.w += b0.w;
        a1.x += b1.x; a1.y += b1.y; a1.z += b1.z; a1.w += b1.w;
    }
    short8 o;
    o[0] = f2bf(a0.x * inv); o[1] = f2bf(a0.y * inv);
    o[2] = f2bf(a0.z * inv); o[3] = f2bf(a0.w * inv);
    o[4] = f2bf(a1.x * inv); o[5] = f2bf(a1.y * inv);
    o[6] = f2bf(a1.z * inv); o[7] = f2bf(a1.w * inv);
    // swizzle-packed dst: [mb][kt][r'][p] (K=512 -> 16 kt per mb)
    const int mb = r >> 6, rm = r & 63;
    const int kt = c >> 5, u = (c >> 3) & 3;
    const int rp = rm >> 1;
    const int up = ((rm & 1) << 2) | u;
    const int p  = up ^ (rp & 7);
    *(short8*)(attB + ((size_t)(mb * 16 + kt)) * 2048 + rp * 64 + p * 8) = o;
}

// ---------------------------------------------------------------------------
// Kernel 3: out = attB @ Wo + bo -> fp32. Grid (16, 64), single wave,
// triple-buffer vmcnt(8). Swizzle-packed attB/wot -> conflict-free.
// ---------------------------------------------------------------------------
__global__ __launch_bounds__(64) void out_mfma(
    const short* __restrict__ attB, const short* __restrict__ wot,
    const float* __restrict__ bo, float* __restrict__ out)
{
    __shared__ short As[3][64 * 32];      // 4KB per buffer
    __shared__ short Bs[3][64 * 32];
    const int nb = blockIdx.x;            // 0..15 (64-col tile)
    const int mb = blockIdx.y;            // 0..63
    const int n0 = nb << 6;
    const int m0 = mb << 6;
    const int lane = threadIdx.x;
    const int l = lane & 15, quad = lane >> 4;

    const short* gA = attB + (size_t)mb * 32768 + lane * 8;
    const short* gB = wot  + (size_t)nb * 32768 + lane * 8;

    auto STAGE = [&](int bb, int kk) {
        const int k0 = kk << 11;
        #pragma unroll
        for (int t = 0; t < 4; ++t) {
            gld_lds16(gA + k0 + t * 512, &As[bb][t << 9]);
            gld_lds16(gB + k0 + t * 512, &Bs[bb][t << 9]);
        }
    };

    STAGE(0, 0);
    STAGE(1, 1);
    asm volatile("s_waitcnt vmcnt(8)" ::: "memory");

    const f32x4 z4 = {0.f, 0.f, 0.f, 0.f};
    f32x4 acc[4][4];
    #pragma unroll
    for (int i = 0; i < 4; ++i)
        #pragma unroll
        for (int j = 0; j < 4; ++j) acc[i][j] = z4;

    const int rbase = (l >> 1) << 6;
    const int pA = (((((l & 1) << 2) | quad) ^ ((l >> 1) & 7)) << 3);
    const int rdo = rbase + pA;

    int cb = 0, sb = 2;
    #pragma unroll 1
    for (int kt = 0; kt < 16; ++kt) {
        STAGE(sb, (kt + 2) & 15);         // wrap re-stage at kt=14,15: harmless
        const short* Al = &As[cb][0];
        const short* Bl = &Bs[cb][0];
        short8 af[4], bfr[4];
        #pragma unroll
        for (int i = 0; i < 4; ++i)
            af[i] = *(const short8*)(Al + (i << 9) + rdo);
        #pragma unroll
        for (int j = 0; j < 4; ++j)
            bfr[j] = *(const short8*)(Bl + (j << 9) + rdo);
        #pragma unroll
        for (int i = 0; i < 4; ++i)
            #pragma unroll
            for (int j = 0; j < 4; ++j)
                acc[i][j] = MFMA(af[i], bfr[j], acc[i][j]);
        asm volatile("s_waitcnt vmcnt(8)" ::: "memory");
        cb = (cb == 2) ? 0 : cb + 1;
        sb = (sb == 2) ? 0 : sb + 1;
    }

    float bcol[4];
    #pragma unroll
    for (int nt = 0; nt < 4; ++nt) bcol[nt] = bo[n0 + (nt << 4) + l];
    #pragma unroll
    for (int i = 0; i < 4; ++i)
        #pragma unroll
        for (int reg = 0; reg < 4; ++reg) {
            const int m = m0 + (i << 4) + (quad << 2) + reg;
            float* o = out + (size_t)m * 1024 + n0 + l;
            #pragma unroll
            for (int nt = 0; nt < 4; ++nt)
                o[nt << 4] = acc[i][nt][reg] + bcol[nt];
        }
}

// ---------------------------------------------------------------------------
extern "C" void kernel_launch(void* const* d_in, const int* in_sizes, int n_in,
                              void* d_out, int out_size, void* d_ws, size_t ws_size,
                              hipStream_t stream) {
    const float* xr = (const float*)d_in[0];
    const float* xi = (const float*)d_in[1];
    const float* Wq = (const float*)d_in[2];
    const float* bq = (const float*)d_in[3];
    const float* Wk = (const float*)d_in[4];
    const float* bk = (const float*)d_in[5];
    const float* Wv = (const float*)d_in[6];
    const float* bv = (const float*)d_in[7];
    const float* Wo = (const float*)d_in[8];
    const float* bo = (const float*)d_in[9];
    float* out = (float*)d_out;

    short* base = (short*)d_ws;
    short* xb   = base;                      // 4096*1024 swizzle-packed
    short* wqt  = xb  + 4194304;             // wcat: 3 x 512*1024 packed
    short* wot  = wqt + 1572864;             // 1024*512 packed
    short* spW  = wot + 524288;              // 16*2048*64 linear
    short* sqW  = spW + 2097152;             // pre-swizzled
    short* vtW  = sqW + 2097152;             // [b,h,d,s] pi+XOR
    short* attB = vtW + 2097152;             // 4096*512 swizzle-packed
    float* pnum = (float*)(attB + 2097152);  // 4 x 4096*512 f32 = 32MB
    float* pden = pnum + 4 * 2097152;        // 4 x 16*2048 f32
    // total ~= 28MB + 32MB + 0.5MB ~= 60.5MB

    hipLaunchKernelGGL(prep_all, dim3(4096), dim3(256), 0, stream,
                       xr, xi, xb, Wq, Wk, Wv, Wo, wqt, wot);
    hipLaunchKernelGGL(qkv_mfma, dim3(24, 64), dim3(64), 0, stream,
                       xb, wqt, bq, bk, bv, spW, sqW, vtW);
    hipLaunchKernelGGL(attn_mfma, dim3(16, 16, 4), dim3(256), 0, stream,
                       spW, sqW, vtW, pnum, pden);
    hipLaunchKernelGGL(combine_attn, dim3(1024), dim3(256), 0, stream,
                       pnum, pden, attB);
    hipLaunchKernelGGL(out_mfma, dim3(16, 64), dim3(64), 0, stream,
                       attB, wot, bo, out);
}